// Round 3
// baseline (851.730 us; speedup 1.0000x reference)
//
#include <hip/hip_runtime.h>

#define N_NODESC 50000
#define N_EDGESC 800000
#define XD 64
#define HIDD 128
#define CTXD 64
#define OUTD 64
#define NBINS 50176   // 1024*49 >= N_NODESC

typedef __bf16 bf16x8 __attribute__((ext_vector_type(8)));
typedef float f32x4 __attribute__((ext_vector_type(4)));

__device__ __forceinline__ unsigned short f2bf(float x) {
    unsigned u = __builtin_bit_cast(unsigned, x);
    unsigned r = u + 0x7FFFu + ((u >> 16) & 1u);
    return (unsigned short)(r >> 16);
}
__device__ __forceinline__ unsigned int pack2(float lo, float hi) {
    return (unsigned int)f2bf(lo) | ((unsigned int)f2bf(hi) << 16);
}

// ---------------------------------------------------------------------------
// Sort step 1: histogram of edge rows
// ---------------------------------------------------------------------------
__global__ __launch_bounds__(256) void hist_k(const int* __restrict__ ei,
                                              int* __restrict__ hist)
{
    int e = blockIdx.x * 256 + threadIdx.x;
    if (e < N_EDGESC) atomicAdd(&hist[ei[e]], 1);
}

// ---------------------------------------------------------------------------
// Sort step 2: exclusive prefix sum over 50k bins (1 block, 1024 threads,
// 49 bins/thread), writes head[] (scatter cursors) and cnt_f[] (float counts).
// ---------------------------------------------------------------------------
__global__ __launch_bounds__(1024) void scan_k(const int* __restrict__ hist,
                                               int* __restrict__ head,
                                               float* __restrict__ cnt_f)
{
    __shared__ int ps[1024];
    const int t = threadIdx.x;
    const int base = t * 49;
    int s = 0;
    for (int i = 0; i < 49; ++i) {
        int idx = base + i;
        if (idx < N_NODESC) s += hist[idx];
    }
    ps[t] = s;
    __syncthreads();
    for (int off = 1; off < 1024; off <<= 1) {
        int u = (t >= off) ? ps[t - off] : 0;
        __syncthreads();
        ps[t] += u;
        __syncthreads();
    }
    int run = ps[t] - s;   // exclusive
    for (int i = 0; i < 49; ++i) {
        int idx = base + i;
        if (idx < N_NODESC) {
            int h = hist[idx];
            head[idx] = run;
            cnt_f[idx] = (float)h;
            run += h;
        }
    }
}

// ---------------------------------------------------------------------------
// Sort step 3: scatter edges into row-sorted er[] / ec[]
// ---------------------------------------------------------------------------
__global__ __launch_bounds__(256) void scatter_k(const int* __restrict__ ei,
                                                 int* __restrict__ head,
                                                 int* __restrict__ er,
                                                 int* __restrict__ ec)
{
    int e = blockIdx.x * 256 + threadIdx.x;
    if (e >= N_EDGESC) return;
    int row = ei[e];
    int col = ei[N_EDGESC + e];
    int p = atomicAdd(&head[row], 1);
    er[p] = row;
    ec[p] = col;
}

// ---------------------------------------------------------------------------
// Prep: bf16 weight transposes (as round 2).
// ---------------------------------------------------------------------------
__global__ void prep_weights(const float* __restrict__ l2m_w1,
                             const float* __restrict__ l2m_w2,
                             const float* __restrict__ l1m_w2,
                             unsigned short* __restrict__ w1t2,
                             unsigned short* __restrict__ w2t2,
                             unsigned short* __restrict__ w2t1)
{
    int i0 = blockIdx.x * 256 + threadIdx.x;
    int stride = gridDim.x * 256;
    for (int idx = i0; idx < 128 * 224; idx += stride) {
        int n = idx / 224, k = idx - n * 224;
        float v = 0.f;
        if (k < 194) {
            int kk = (k < 128) ? k : (k < 192 ? k + 2 : (k == 192 ? 128 : 129));
            v = l2m_w1[kk * 128 + n];
        }
        w1t2[idx] = f2bf(v);
    }
    for (int idx = i0; idx < 64 * 128; idx += stride) {
        int n = idx >> 7, k = idx & 127;
        w2t2[idx] = f2bf(l2m_w2[k * 64 + n]);
        w2t1[idx] = f2bf(l1m_w2[k * 64 + n]);
    }
}

// ---------------------------------------------------------------------------
// L1 edges (sorted): hidden via VALU (K=2), MFMA layer 2, LDS run-merge
// reduce, few atomics.
// ---------------------------------------------------------------------------
__global__ __launch_bounds__(512) void l1_mfma(
    const int* __restrict__ er, const int* __restrict__ ec,
    const float* __restrict__ pos,
    const float* __restrict__ w1, const float* __restrict__ b1,
    const unsigned short* __restrict__ w2t,
    float* __restrict__ sum1)
{
    __shared__ unsigned short H[128 * 136];   // aliased as float [128][68] later
    __shared__ float pd[128][2];
    __shared__ int rows_s[128];
    const int tid = threadIdx.x;
    const int eb = blockIdx.x * 128;

    if (tid < 128) {
        int e = eb + tid;
        int ri = er[e], ci = ec[e];
        rows_s[tid] = ri;
        float2 pr = *(const float2*)(pos + 2 * ri);
        float2 pc = *(const float2*)(pos + 2 * ci);
        pd[tid][0] = pc.x - pr.x;
        pd[tid][1] = pc.y - pr.y;
    }
    __syncthreads();

    {   // hidden layer, 4 threads per edge, 32 hidden units each
        int e_loc = tid >> 2, part = tid & 3;
        float px = pd[e_loc][0], py = pd[e_loc][1];
        int jb = part * 32;
        unsigned int* Hw = (unsigned int*)H + e_loc * 68 + (jb >> 1);
        #pragma unroll
        for (int q = 0; q < 8; ++q) {
            float4 wa = *(const float4*)(w1 + jb + 4 * q);
            float4 wb = *(const float4*)(w1 + 128 + jb + 4 * q);
            float4 bb = *(const float4*)(b1 + jb + 4 * q);
            float h0 = fmaxf(fmaf(px, wa.x, fmaf(py, wb.x, bb.x)), 0.f);
            float h1 = fmaxf(fmaf(px, wa.y, fmaf(py, wb.y, bb.y)), 0.f);
            float h2 = fmaxf(fmaf(px, wa.z, fmaf(py, wb.z, bb.z)), 0.f);
            float h3 = fmaxf(fmaf(px, wa.w, fmaf(py, wb.w, bb.w)), 0.f);
            Hw[2 * q]     = pack2(h0, h1);
            Hw[2 * q + 1] = pack2(h2, h3);
        }
    }
    __syncthreads();

    const int lane = tid & 63;
    const int l15 = lane & 15, l4 = lane >> 4;
    const int wave = tid >> 6;
    const int mh = (wave >> 2) * 64;
    const int nw = (wave & 3) * 16;

    f32x4 acc[4];
    #pragma unroll
    for (int m = 0; m < 4; ++m) acc[m] = (f32x4){0.f, 0.f, 0.f, 0.f};

    #pragma unroll
    for (int k = 0; k < 4; ++k) {
        int kb = k * 32 + l4 * 8;
        bf16x8 b = *(const bf16x8*)(w2t + (nw + l15) * 128 + kb);
        #pragma unroll
        for (int m = 0; m < 4; ++m) {
            bf16x8 a = *(const bf16x8*)(H + (mh + m * 16 + l15) * 136 + kb);
            acc[m] = __builtin_amdgcn_mfma_f32_16x16x32_bf16(a, b, acc[m], 0, 0, 0);
        }
    }
    __syncthreads();     // all H reads done; reuse H as f32 scratch
    float* S = (float*)H;    // [128][68]
    #pragma unroll
    for (int m = 0; m < 4; ++m) {
        int rb = mh + m * 16 + l4 * 4;
        #pragma unroll
        for (int r = 0; r < 4; ++r)
            S[(rb + r) * 68 + nw + l15] = acc[m][r];
    }
    __syncthreads();
    {   // run-merged segment reduction: thread = (col, 16-edge group)
        int c = tid & 63, g = tid >> 6;
        int e0 = g * 16;
        int cur = rows_s[e0];
        float v = S[e0 * 68 + c];
        for (int r = 1; r < 16; ++r) {
            int rr = rows_s[e0 + r];
            float u = S[(e0 + r) * 68 + c];
            if (rr == cur) { v += u; }
            else { unsafeAtomicAdd(sum1 + (size_t)cur * CTXD + c, v); cur = rr; v = u; }
        }
        unsafeAtomicAdd(sum1 + (size_t)cur * CTXD + c, v);
    }
}

// ---------------------------------------------------------------------------
// L2 edges (sorted): MFMA 224->128 relu -> MFMA 128->64, LDS run-merge reduce.
// Dynamic LDS: A[128][248] | W[128][248] | H[128][136] | rows[128]
// ---------------------------------------------------------------------------
#define A_OFF 0
#define W_OFF 63488
#define H_OFF 126976
#define R_OFF 161792
#define L2_LDS 162304

__global__ __launch_bounds__(512) void l2_mfma(
    const int* __restrict__ er, const int* __restrict__ ec,
    const float* __restrict__ x,
    const float* __restrict__ pos, const float* __restrict__ ctxin,
    const unsigned short* __restrict__ w1t, const float* __restrict__ b1,
    const unsigned short* __restrict__ w2t,
    float* __restrict__ sum2)
{
    extern __shared__ char smem[];
    const int tid = threadIdx.x;
    const int eb = blockIdx.x * 128;

    // stage W1t: [128][224] bf16 global -> [128 rows][248 stride] LDS
    {
        const int4* src = (const int4*)w1t;
        for (int i = tid; i < 3584; i += 512) {
            int n = i / 28, c = i - n * 28;
            *(int4*)(smem + W_OFF + n * 496 + c * 16) = src[i];
        }
    }
    // gather A tile: 4 threads per edge
    {
        int e_loc = tid >> 2, part = tid & 3;
        int e = eb + e_loc;
        int ri = er[e], ci = ec[e];
        unsigned int* Aw = (unsigned int*)(smem + A_OFF) + e_loc * 124;
        if (part == 0) {
            const float4* xs = (const float4*)(x + (size_t)ri * XD);
            #pragma unroll
            for (int q = 0; q < 16; ++q) {
                float4 v = xs[q];
                Aw[2 * q]     = pack2(v.x, v.y);
                Aw[2 * q + 1] = pack2(v.z, v.w);
            }
        } else if (part == 1) {
            const float4* xr = (const float4*)(x + (size_t)ri * XD);
            const float4* xc = (const float4*)(x + (size_t)ci * XD);
            #pragma unroll
            for (int q = 0; q < 16; ++q) {
                float4 a = xr[q], b = xc[q];
                Aw[32 + 2 * q]     = pack2(b.x - a.x, b.y - a.y);
                Aw[32 + 2 * q + 1] = pack2(b.z - a.z, b.w - a.w);
            }
        } else if (part == 2) {
            const float4* cs = (const float4*)(ctxin + (size_t)ri * CTXD);
            #pragma unroll
            for (int q = 0; q < 16; ++q) {
                float4 v = cs[q];
                Aw[64 + 2 * q]     = pack2(v.x, v.y);
                Aw[64 + 2 * q + 1] = pack2(v.z, v.w);
            }
        } else {
            ((int*)(smem + R_OFF))[e_loc] = ri;
            float2 pr = *(const float2*)(pos + 2 * ri);
            float2 pc = *(const float2*)(pos + 2 * ci);
            Aw[96] = pack2(pc.x - pr.x, pc.y - pr.y);
            #pragma unroll
            for (int z = 0; z < 15; ++z) Aw[97 + z] = 0u;
        }
    }
    __syncthreads();

    const int lane = tid & 63;
    const int l15 = lane & 15, l4 = lane >> 4;
    const int wave = tid >> 6;
    const int mh = (wave >> 2) * 64;          // edge half
    const int nq = (wave & 3) * 32;           // hidden quad (layer 1)

    f32x4 acc[4][2];
    #pragma unroll
    for (int m = 0; m < 4; ++m)
        #pragma unroll
        for (int n = 0; n < 2; ++n) acc[m][n] = (f32x4){0.f, 0.f, 0.f, 0.f};

    #pragma unroll
    for (int k = 0; k < 7; ++k) {
        int koff = k * 64 + l4 * 16;          // byte offset within row
        bf16x8 b0 = *(const bf16x8*)(smem + W_OFF + (nq + l15) * 496 + koff);
        bf16x8 b1f = *(const bf16x8*)(smem + W_OFF + (nq + 16 + l15) * 496 + koff);
        #pragma unroll
        for (int m = 0; m < 4; ++m) {
            bf16x8 a = *(const bf16x8*)(smem + A_OFF + (mh + m * 16 + l15) * 496 + koff);
            acc[m][0] = __builtin_amdgcn_mfma_f32_16x16x32_bf16(a, b0, acc[m][0], 0, 0, 0);
            acc[m][1] = __builtin_amdgcn_mfma_f32_16x16x32_bf16(a, b1f, acc[m][1], 0, 0, 0);
        }
    }
    // epilogue: +b1, relu, bf16, write H [edge][hidden]
    float bv0 = b1[nq + l15];
    float bv1 = b1[nq + 16 + l15];
    #pragma unroll
    for (int m = 0; m < 4; ++m) {
        int rb = mh + m * 16 + l4 * 4;
        #pragma unroll
        for (int n = 0; n < 2; ++n) {
            float bv = n ? bv1 : bv0;
            int col = nq + n * 16 + l15;
            #pragma unroll
            for (int r = 0; r < 4; ++r) {
                float h = fmaxf(acc[m][n][r] + bv, 0.f);
                *(unsigned short*)(smem + H_OFF + (rb + r) * 272 + col * 2) = f2bf(h);
            }
        }
    }
    __syncthreads();

    // layer 2: H[128x128] @ W2t^T -> [128x64]
    const int nw = (wave & 3) * 16;
    f32x4 acc2[4];
    #pragma unroll
    for (int m = 0; m < 4; ++m) acc2[m] = (f32x4){0.f, 0.f, 0.f, 0.f};

    #pragma unroll
    for (int k = 0; k < 4; ++k) {
        int kb = k * 32 + l4 * 8;
        bf16x8 b = *(const bf16x8*)(w2t + (nw + l15) * 128 + kb);
        #pragma unroll
        for (int m = 0; m < 4; ++m) {
            bf16x8 a = *(const bf16x8*)(smem + H_OFF + (mh + m * 16 + l15) * 272 + kb * 2);
            acc2[m] = __builtin_amdgcn_mfma_f32_16x16x32_bf16(a, b, acc2[m], 0, 0, 0);
        }
    }
    __syncthreads();     // all H reads done; reuse H region as f32 scratch
    float* S = (float*)(smem + H_OFF);   // [128][68]
    #pragma unroll
    for (int m = 0; m < 4; ++m) {
        int rb = mh + m * 16 + l4 * 4;
        #pragma unroll
        for (int r = 0; r < 4; ++r)
            S[(rb + r) * 68 + nw + l15] = acc2[m][r];
    }
    __syncthreads();
    {
        const int* rows_p = (const int*)(smem + R_OFF);
        int c = tid & 63, g = tid >> 6;
        int e0 = g * 16;
        int cur = rows_p[e0];
        float v = S[e0 * 68 + c];
        for (int r = 1; r < 16; ++r) {
            int rr = rows_p[e0 + r];
            float u = S[(e0 + r) * 68 + c];
            if (rr == cur) { v += u; }
            else { unsafeAtomicAdd(sum2 + (size_t)cur * OUTD + c, v); cur = rr; v = u; }
        }
        unsafeAtomicAdd(sum2 + (size_t)cur * OUTD + c, v);
    }
}

// ---------------------------------------------------------------------------
// per-node ctx = MLP(mean(m1) + l1m_b2)  (64 -> 128 -> 64)  [fp32]
// ---------------------------------------------------------------------------
__global__ __launch_bounds__(256) void ctx_nodes(
    const float* __restrict__ sum1, const float* __restrict__ cnt,
    const float* __restrict__ mb2, const float* __restrict__ aw1,
    const float* __restrict__ ab1, const float* __restrict__ aw2,
    const float* __restrict__ ab2, float* __restrict__ ctxout)
{
    __shared__ float w1t[HIDD * 68];   // padded stride 68 floats
    for (int idx = threadIdx.x; idx < CTXD * HIDD; idx += 256) {
        int i = idx >> 7;
        int j = idx & (HIDD - 1);
        w1t[j * 68 + i] = aw1[idx];
    }
    __syncthreads();

    int n = blockIdx.x * 256 + threadIdx.x;
    if (n >= N_NODESC) return;
    float inv = 1.0f / fmaxf(cnt[n], 1.0f);

    float a[CTXD];
    const float4* s1 = reinterpret_cast<const float4*>(sum1 + (size_t)n * CTXD);
    const float4* mb = reinterpret_cast<const float4*>(mb2);
    #pragma unroll
    for (int i4 = 0; i4 < CTXD / 4; ++i4) {
        float4 v = s1[i4]; float4 m = mb[i4];
        a[4 * i4 + 0] = fmaf(v.x, inv, m.x);
        a[4 * i4 + 1] = fmaf(v.y, inv, m.y);
        a[4 * i4 + 2] = fmaf(v.z, inv, m.z);
        a[4 * i4 + 3] = fmaf(v.w, inv, m.w);
    }
    float o[OUTD];
    const float4* b2v = reinterpret_cast<const float4*>(ab2);
    #pragma unroll
    for (int k4 = 0; k4 < OUTD / 4; ++k4) {
        float4 b = b2v[k4];
        o[4 * k4 + 0] = b.x; o[4 * k4 + 1] = b.y;
        o[4 * k4 + 2] = b.z; o[4 * k4 + 3] = b.w;
    }
    for (int j = 0; j < HIDD; ++j) {
        float hj = ab1[j];
        const float4* wr = reinterpret_cast<const float4*>(&w1t[j * 68]);
        #pragma unroll
        for (int i4 = 0; i4 < CTXD / 4; ++i4) {
            float4 w = wr[i4];
            hj = fmaf(a[4 * i4 + 0], w.x, hj);
            hj = fmaf(a[4 * i4 + 1], w.y, hj);
            hj = fmaf(a[4 * i4 + 2], w.z, hj);
            hj = fmaf(a[4 * i4 + 3], w.w, hj);
        }
        hj = fmaxf(hj, 0.f);
        const float4* w2r = reinterpret_cast<const float4*>(aw2 + j * OUTD);
        #pragma unroll
        for (int k4 = 0; k4 < OUTD / 4; ++k4) {
            float4 w = w2r[k4];
            o[4 * k4 + 0] = fmaf(hj, w.x, o[4 * k4 + 0]);
            o[4 * k4 + 1] = fmaf(hj, w.y, o[4 * k4 + 1]);
            o[4 * k4 + 2] = fmaf(hj, w.z, o[4 * k4 + 2]);
            o[4 * k4 + 3] = fmaf(hj, w.w, o[4 * k4 + 3]);
        }
    }
    float4* outp = reinterpret_cast<float4*>(ctxout + (size_t)n * CTXD);
    #pragma unroll
    for (int k4 = 0; k4 < CTXD / 4; ++k4)
        outp[k4] = make_float4(o[4 * k4], o[4 * k4 + 1], o[4 * k4 + 2], o[4 * k4 + 3]);
}

// ---------------------------------------------------------------------------
// per-node out = MLP([x, mean(m2)+l2m_b2])  (128 -> 128 -> 64) [fp32]
// ---------------------------------------------------------------------------
__global__ __launch_bounds__(256) void out_nodes(
    const float* __restrict__ x, const float* __restrict__ sum2,
    const float* __restrict__ cnt, const float* __restrict__ mb2,
    const float* __restrict__ aw1, const float* __restrict__ ab1,
    const float* __restrict__ aw2, const float* __restrict__ ab2,
    float* __restrict__ out)
{
    extern __shared__ float w1t[];   // padded stride 132 floats
    for (int idx = threadIdx.x; idx < HIDD * HIDD; idx += 256) {
        int i = idx >> 7;
        int j = idx & (HIDD - 1);
        w1t[j * 132 + i] = aw1[idx];
    }
    __syncthreads();

    int n = blockIdx.x * 256 + threadIdx.x;
    if (n >= N_NODESC) return;
    float inv = 1.0f / fmaxf(cnt[n], 1.0f);

    float a[HIDD];
    const float4* xv = reinterpret_cast<const float4*>(x + (size_t)n * XD);
    #pragma unroll
    for (int i4 = 0; i4 < XD / 4; ++i4) {
        float4 v = xv[i4];
        a[4 * i4 + 0] = v.x; a[4 * i4 + 1] = v.y;
        a[4 * i4 + 2] = v.z; a[4 * i4 + 3] = v.w;
    }
    const float4* s2 = reinterpret_cast<const float4*>(sum2 + (size_t)n * OUTD);
    const float4* mb = reinterpret_cast<const float4*>(mb2);
    #pragma unroll
    for (int i4 = 0; i4 < OUTD / 4; ++i4) {
        float4 v = s2[i4]; float4 m = mb[i4];
        a[XD + 4 * i4 + 0] = fmaf(v.x, inv, m.x);
        a[XD + 4 * i4 + 1] = fmaf(v.y, inv, m.y);
        a[XD + 4 * i4 + 2] = fmaf(v.z, inv, m.z);
        a[XD + 4 * i4 + 3] = fmaf(v.w, inv, m.w);
    }
    float o[OUTD];
    const float4* b2v = reinterpret_cast<const float4*>(ab2);
    #pragma unroll
    for (int k4 = 0; k4 < OUTD / 4; ++k4) {
        float4 b = b2v[k4];
        o[4 * k4 + 0] = b.x; o[4 * k4 + 1] = b.y;
        o[4 * k4 + 2] = b.z; o[4 * k4 + 3] = b.w;
    }
    for (int j = 0; j < HIDD; ++j) {
        float hj = ab1[j];
        const float4* wr = reinterpret_cast<const float4*>(&w1t[j * 132]);
        #pragma unroll
        for (int i4 = 0; i4 < HIDD / 4; ++i4) {
            float4 w = wr[i4];
            hj = fmaf(a[4 * i4 + 0], w.x, hj);
            hj = fmaf(a[4 * i4 + 1], w.y, hj);
            hj = fmaf(a[4 * i4 + 2], w.z, hj);
            hj = fmaf(a[4 * i4 + 3], w.w, hj);
        }
        hj = fmaxf(hj, 0.f);
        const float4* w2r = reinterpret_cast<const float4*>(aw2 + j * OUTD);
        #pragma unroll
        for (int k4 = 0; k4 < OUTD / 4; ++k4) {
            float4 w = w2r[k4];
            o[4 * k4 + 0] = fmaf(hj, w.x, o[4 * k4 + 0]);
            o[4 * k4 + 1] = fmaf(hj, w.y, o[4 * k4 + 1]);
            o[4 * k4 + 2] = fmaf(hj, w.z, o[4 * k4 + 2]);
            o[4 * k4 + 3] = fmaf(hj, w.w, o[4 * k4 + 3]);
        }
    }
    float4* outp = reinterpret_cast<float4*>(out + (size_t)n * OUTD);
    #pragma unroll
    for (int k4 = 0; k4 < OUTD / 4; ++k4)
        outp[k4] = make_float4(o[4 * k4], o[4 * k4 + 1], o[4 * k4 + 2], o[4 * k4 + 3]);
}

// ---------------------------------------------------------------------------
extern "C" void kernel_launch(void* const* d_in, const int* in_sizes, int n_in,
                              void* d_out, int out_size, void* d_ws, size_t ws_size,
                              hipStream_t stream)
{
    const float* x      = (const float*)d_in[0];
    const float* pos    = (const float*)d_in[1];
    const int*   ei     = (const int*)  d_in[2];
    const float* l1m_w1 = (const float*)d_in[3];
    const float* l1m_b1 = (const float*)d_in[4];
    const float* l1m_w2 = (const float*)d_in[5];
    const float* l1m_b2 = (const float*)d_in[6];
    const float* l1a_w1 = (const float*)d_in[7];
    const float* l1a_b1 = (const float*)d_in[8];
    const float* l1a_w2 = (const float*)d_in[9];
    const float* l1a_b2 = (const float*)d_in[10];
    const float* l2m_w1 = (const float*)d_in[11];
    const float* l2m_b1 = (const float*)d_in[12];
    const float* l2m_w2 = (const float*)d_in[13];
    const float* l2m_b2 = (const float*)d_in[14];
    const float* l2a_w1 = (const float*)d_in[15];
    const float* l2a_b1 = (const float*)d_in[16];
    const float* l2a_w2 = (const float*)d_in[17];
    const float* l2a_b2 = (const float*)d_in[18];

    float* ws   = (float*)d_ws;
    float* sum1 = ws;                                   // [N][64]
    float* sum2 = sum1 + (size_t)N_NODESC * CTXD;       // [N][64]
    float* ctxb = sum2 + (size_t)N_NODESC * OUTD;       // [N][64]
    float* cnt_f = ctxb + (size_t)N_NODESC * CTXD;      // [NBINS]
    unsigned short* w1t2 = (unsigned short*)(cnt_f + NBINS);  // 128*224
    unsigned short* w2t2 = w1t2 + 128 * 224;            // 64*128
    unsigned short* w2t1 = w2t2 + 64 * 128;             // 64*128
    int* hist = (int*)(w2t1 + 64 * 128);                // [NBINS]
    int* head = hist + NBINS;                           // [NBINS]
    int* er   = head + NBINS;                           // [E]
    int* ec   = er + N_EDGESC;                          // [E]

    // zero sum1+sum2 (contiguous) and hist
    hipMemsetAsync(d_ws, 0, (size_t)2 * N_NODESC * 64 * sizeof(float), stream);
    hipMemsetAsync(hist, 0, NBINS * sizeof(int), stream);

    hipFuncSetAttribute((const void*)l2_mfma,
                        hipFuncAttributeMaxDynamicSharedMemorySize, L2_LDS);
    hipFuncSetAttribute((const void*)out_nodes,
                        hipFuncAttributeMaxDynamicSharedMemorySize, HIDD * 132 * 4);

    hist_k<<<(N_EDGESC + 255) / 256, 256, 0, stream>>>(ei, hist);
    scan_k<<<1, 1024, 0, stream>>>(hist, head, cnt_f);
    scatter_k<<<(N_EDGESC + 255) / 256, 256, 0, stream>>>(ei, head, er, ec);

    prep_weights<<<64, 256, 0, stream>>>(l2m_w1, l2m_w2, l1m_w2, w1t2, w2t2, w2t1);

    l1_mfma<<<N_EDGESC / 128, 512, 0, stream>>>(
        er, ec, pos, l1m_w1, l1m_b1, w2t1, sum1);

    ctx_nodes<<<(N_NODESC + 255) / 256, 256, 0, stream>>>(
        sum1, cnt_f, l1m_b2, l1a_w1, l1a_b1, l1a_w2, l1a_b2, ctxb);

    l2_mfma<<<N_EDGESC / 128, 512, L2_LDS, stream>>>(
        er, ec, x, pos, ctxb, w1t2, l2m_b1, w2t2, sum2);

    out_nodes<<<(N_NODESC + 255) / 256, 256, HIDD * 132 * 4, stream>>>(
        x, sum2, cnt_f, l2m_b2, l2a_w1, l2a_b1, l2a_w2, l2a_b2, (float*)d_out);
}

// Round 4
// 386.072 us; speedup vs baseline: 2.2061x; 2.2061x over previous
//
#include <hip/hip_runtime.h>

#define N_NODESC 50000
#define N_EDGESC 800000
#define XD 64
#define HIDD 128
#define CTXD 64
#define OUTD 64
#define NBINS 50176   // 196 * 256

typedef __bf16 bf16x8 __attribute__((ext_vector_type(8)));
typedef float f32x4 __attribute__((ext_vector_type(4)));

__device__ __forceinline__ unsigned short f2bf(float x) {
    unsigned u = __builtin_bit_cast(unsigned, x);
    unsigned r = u + 0x7FFFu + ((u >> 16) & 1u);
    return (unsigned short)(r >> 16);
}
__device__ __forceinline__ unsigned int pack2(float lo, float hi) {
    return (unsigned int)f2bf(lo) | ((unsigned int)f2bf(hi) << 16);
}
__device__ __forceinline__ float bflo(unsigned v) {
    return __builtin_bit_cast(float, v << 16);
}
__device__ __forceinline__ float bfhi(unsigned v) {
    return __builtin_bit_cast(float, v & 0xFFFF0000u);
}

// ---------------------------------------------------------------------------
// Sort: histogram
// ---------------------------------------------------------------------------
__global__ __launch_bounds__(256) void hist_k(const int* __restrict__ ei,
                                              int* __restrict__ hist)
{
    int e = blockIdx.x * 256 + threadIdx.x;
    if (e < N_EDGESC) atomicAdd(&hist[ei[e]], 1);
}

// Hierarchical scan: (a) per-block totals, (b) scan totals, (c) per-bin heads
__global__ __launch_bounds__(256) void scan_a(const int* __restrict__ hist,
                                              int* __restrict__ bsums)
{
    __shared__ int ps[256];
    int t = threadIdx.x;
    int v = hist[blockIdx.x * 256 + t];
    ps[t] = v;
    __syncthreads();
    for (int off = 1; off < 256; off <<= 1) {
        int u = (t >= off) ? ps[t - off] : 0;
        __syncthreads();
        ps[t] += u;
        __syncthreads();
    }
    if (t == 255) bsums[blockIdx.x] = ps[255];
}

__global__ __launch_bounds__(256) void scan_b(int* __restrict__ bsums)
{
    __shared__ int ps[256];
    int t = threadIdx.x;
    int v = (t < 196) ? bsums[t] : 0;
    ps[t] = v;
    __syncthreads();
    for (int off = 1; off < 256; off <<= 1) {
        int u = (t >= off) ? ps[t - off] : 0;
        __syncthreads();
        ps[t] += u;
        __syncthreads();
    }
    if (t < 196) bsums[t] = ps[t] - v;   // exclusive
}

__global__ __launch_bounds__(256) void scan_c(const int* __restrict__ hist,
                                              const int* __restrict__ bsums,
                                              int* __restrict__ head,
                                              float* __restrict__ cnt_f)
{
    __shared__ int ps[256];
    int t = threadIdx.x;
    int bin = blockIdx.x * 256 + t;
    int v = hist[bin];
    ps[t] = v;
    __syncthreads();
    for (int off = 1; off < 256; off <<= 1) {
        int u = (t >= off) ? ps[t - off] : 0;
        __syncthreads();
        ps[t] += u;
        __syncthreads();
    }
    head[bin] = ps[t] - v + bsums[blockIdx.x];
    cnt_f[bin] = (float)v;
}

__global__ __launch_bounds__(256) void scatter_k(const int* __restrict__ ei,
                                                 int* __restrict__ head,
                                                 int* __restrict__ er,
                                                 int* __restrict__ ec)
{
    int e = blockIdx.x * 256 + threadIdx.x;
    if (e >= N_EDGESC) return;
    int row = ei[e];
    int col = ei[N_EDGESC + e];
    int p = atomicAdd(&head[row], 1);
    er[p] = row;
    ec[p] = col;
}

// ---------------------------------------------------------------------------
// Prep: all bf16 weight transposes / combinations.
// l2m_w1 rows: W1a=0..63(x_i) W1b=64..127(dx) W1c=128..129(pd) W1d=130..193(ctx)
// wp [128n][224k]: k0-63: W1a-W1b ; k64-127: W1d ; k128-129: -W1c ; rest 0
// wq [128n][224k]: k0-63: W1b ; k128-129: +W1c ; rest 0
// ---------------------------------------------------------------------------
__global__ void prep_weights(const float* __restrict__ w1,
                             const float* __restrict__ l2m_w2,
                             const float* __restrict__ l1m_w2,
                             const float* __restrict__ l1a_w1,
                             const float* __restrict__ l1a_w2,
                             const float* __restrict__ l2a_w1,
                             const float* __restrict__ l2a_w2,
                             unsigned short* __restrict__ wp,
                             unsigned short* __restrict__ wq,
                             unsigned short* __restrict__ w2t1,
                             unsigned short* __restrict__ w2t2,
                             unsigned short* __restrict__ aw1t,
                             unsigned short* __restrict__ aw2t,
                             unsigned short* __restrict__ bw1t,
                             unsigned short* __restrict__ bw2t)
{
    int i0 = blockIdx.x * 256 + threadIdx.x;
    int stride = gridDim.x * 256;
    for (int idx = i0; idx < 128 * 224; idx += stride) {
        int n = idx / 224, k = idx - n * 224;
        float vp = 0.f, vq = 0.f;
        if (k < 64)        { vp = w1[k * 128 + n] - w1[(64 + k) * 128 + n];
                             vq = w1[(64 + k) * 128 + n]; }
        else if (k < 128)  { vp = w1[(130 + k - 64) * 128 + n]; }
        else if (k < 130)  { vp = -w1[(128 + (k - 128)) * 128 + n];
                             vq =  w1[(128 + (k - 128)) * 128 + n]; }
        wp[idx] = f2bf(vp);
        wq[idx] = f2bf(vq);
    }
    for (int idx = i0; idx < 64 * 128; idx += stride) {
        int n = idx >> 7, k = idx & 127;
        w2t1[idx] = f2bf(l1m_w2[k * 64 + n]);
        w2t2[idx] = f2bf(l2m_w2[k * 64 + n]);
        aw2t[idx] = f2bf(l1a_w2[k * 64 + n]);
        bw2t[idx] = f2bf(l2a_w2[k * 64 + n]);
    }
    for (int idx = i0; idx < 128 * 64; idx += stride) {
        int n = idx >> 6, k = idx & 63;
        aw1t[idx] = f2bf(l1a_w1[k * 128 + n]);
    }
    for (int idx = i0; idx < 128 * 128; idx += stride) {
        int n = idx >> 7, k = idx & 127;
        bw1t[idx] = f2bf(l2a_w1[k * 128 + n]);
    }
}

// ---------------------------------------------------------------------------
// L1 edges (sorted): VALU hidden (K=2), MFMA layer 2, run-merge reduce.
// ---------------------------------------------------------------------------
__global__ __launch_bounds__(512) void l1_mfma(
    const int* __restrict__ er, const int* __restrict__ ec,
    const float* __restrict__ pos,
    const float* __restrict__ w1, const float* __restrict__ b1,
    const unsigned short* __restrict__ w2t,
    float* __restrict__ sum1)
{
    __shared__ unsigned short H[128 * 136];
    __shared__ float pd[128][2];
    __shared__ int rows_s[128];
    const int tid = threadIdx.x;
    const int eb = blockIdx.x * 128;

    if (tid < 128) {
        int e = eb + tid;
        int ri = er[e], ci = ec[e];
        rows_s[tid] = ri;
        float2 pr = *(const float2*)(pos + 2 * ri);
        float2 pc = *(const float2*)(pos + 2 * ci);
        pd[tid][0] = pc.x - pr.x;
        pd[tid][1] = pc.y - pr.y;
    }
    __syncthreads();

    {
        int e_loc = tid >> 2, part = tid & 3;
        float px = pd[e_loc][0], py = pd[e_loc][1];
        int jb = part * 32;
        unsigned int* Hw = (unsigned int*)H + e_loc * 68 + (jb >> 1);
        #pragma unroll
        for (int q = 0; q < 8; ++q) {
            float4 wa = *(const float4*)(w1 + jb + 4 * q);
            float4 wb = *(const float4*)(w1 + 128 + jb + 4 * q);
            float4 bb = *(const float4*)(b1 + jb + 4 * q);
            float h0 = fmaxf(fmaf(px, wa.x, fmaf(py, wb.x, bb.x)), 0.f);
            float h1 = fmaxf(fmaf(px, wa.y, fmaf(py, wb.y, bb.y)), 0.f);
            float h2 = fmaxf(fmaf(px, wa.z, fmaf(py, wb.z, bb.z)), 0.f);
            float h3 = fmaxf(fmaf(px, wa.w, fmaf(py, wb.w, bb.w)), 0.f);
            Hw[2 * q]     = pack2(h0, h1);
            Hw[2 * q + 1] = pack2(h2, h3);
        }
    }
    __syncthreads();

    const int lane = tid & 63;
    const int l15 = lane & 15, l4 = lane >> 4;
    const int wave = tid >> 6;
    const int mh = (wave >> 2) * 64;
    const int nw = (wave & 3) * 16;

    f32x4 acc[4];
    #pragma unroll
    for (int m = 0; m < 4; ++m) acc[m] = (f32x4){0.f, 0.f, 0.f, 0.f};

    #pragma unroll
    for (int k = 0; k < 4; ++k) {
        int kb = k * 32 + l4 * 8;
        bf16x8 b = *(const bf16x8*)(w2t + (nw + l15) * 128 + kb);
        #pragma unroll
        for (int m = 0; m < 4; ++m) {
            bf16x8 a = *(const bf16x8*)(H + (mh + m * 16 + l15) * 136 + kb);
            acc[m] = __builtin_amdgcn_mfma_f32_16x16x32_bf16(a, b, acc[m], 0, 0, 0);
        }
    }
    __syncthreads();
    float* S = (float*)H;    // [128][68]
    #pragma unroll
    for (int m = 0; m < 4; ++m) {
        int rb = mh + m * 16 + l4 * 4;
        #pragma unroll
        for (int r = 0; r < 4; ++r)
            S[(rb + r) * 68 + nw + l15] = acc[m][r];
    }
    __syncthreads();
    {
        int c = tid & 63, g = tid >> 6;
        int e0 = g * 16;
        int cur = rows_s[e0];
        float v = S[e0 * 68 + c];
        for (int r = 1; r < 16; ++r) {
            int rr = rows_s[e0 + r];
            float u = S[(e0 + r) * 68 + c];
            if (rr == cur) { v += u; }
            else { unsafeAtomicAdd(sum1 + (size_t)cur * CTXD + c, v); cur = rr; v = u; }
        }
        unsafeAtomicAdd(sum1 + (size_t)cur * CTXD + c, v);
    }
}

// ---------------------------------------------------------------------------
// ctx = MLP(mean(m1)+l1m_b2)  (64 -> 128 -> 64), MFMA, 128 nodes/block
// ---------------------------------------------------------------------------
__global__ __launch_bounds__(512) void ctx_mfma(
    const float* __restrict__ sum1, const float* __restrict__ cnt,
    const float* __restrict__ mb2,
    const unsigned short* __restrict__ aw1t, const float* __restrict__ ab1,
    const unsigned short* __restrict__ aw2t, const float* __restrict__ ab2,
    float* __restrict__ ctxout)
{
    __shared__ unsigned short A[128 * 72];
    __shared__ unsigned short H[128 * 136];
    const int tid = threadIdx.x;
    const int nb = blockIdx.x * 128;

    {
        int nl = tid >> 2, part = tid & 3;
        int n = nb + nl; if (n >= N_NODESC) n = N_NODESC - 1;
        float inv = 1.0f / fmaxf(cnt[n], 1.0f);
        const float4* s = (const float4*)(sum1 + (size_t)n * CTXD + part * 16);
        const float4* m = (const float4*)(mb2 + part * 16);
        unsigned* Aw = (unsigned*)A + nl * 36 + part * 8;
        #pragma unroll
        for (int q = 0; q < 4; ++q) {
            float4 v = s[q]; float4 b = m[q];
            Aw[2 * q]     = pack2(fmaf(v.x, inv, b.x), fmaf(v.y, inv, b.y));
            Aw[2 * q + 1] = pack2(fmaf(v.z, inv, b.z), fmaf(v.w, inv, b.w));
        }
    }
    __syncthreads();

    const int lane = tid & 63, l15 = lane & 15, l4 = lane >> 4;
    const int wave = tid >> 6;
    const int mh = (wave >> 2) * 64;
    const int nq = (wave & 3) * 32;

    f32x4 acc[4][2];
    #pragma unroll
    for (int m = 0; m < 4; ++m)
        #pragma unroll
        for (int n = 0; n < 2; ++n) acc[m][n] = (f32x4){0.f, 0.f, 0.f, 0.f};

    #pragma unroll
    for (int kc = 0; kc < 2; ++kc) {
        int kb = kc * 32 + l4 * 8;
        bf16x8 b0 = *(const bf16x8*)(aw1t + (nq + l15) * 64 + kb);
        bf16x8 b1v = *(const bf16x8*)(aw1t + (nq + 16 + l15) * 64 + kb);
        #pragma unroll
        for (int m = 0; m < 4; ++m) {
            bf16x8 a = *(const bf16x8*)(A + (mh + m * 16 + l15) * 72 + kb);
            acc[m][0] = __builtin_amdgcn_mfma_f32_16x16x32_bf16(a, b0, acc[m][0], 0, 0, 0);
            acc[m][1] = __builtin_amdgcn_mfma_f32_16x16x32_bf16(a, b1v, acc[m][1], 0, 0, 0);
        }
    }
    float bv0 = ab1[nq + l15], bv1 = ab1[nq + 16 + l15];
    #pragma unroll
    for (int m = 0; m < 4; ++m) {
        int rb = mh + m * 16 + l4 * 4;
        #pragma unroll
        for (int nn = 0; nn < 2; ++nn) {
            float bv = nn ? bv1 : bv0;
            int col = nq + nn * 16 + l15;
            #pragma unroll
            for (int r = 0; r < 4; ++r)
                H[(rb + r) * 136 + col] = f2bf(fmaxf(acc[m][nn][r] + bv, 0.f));
        }
    }
    __syncthreads();

    const int nw = (wave & 3) * 16;
    f32x4 acc2[4];
    #pragma unroll
    for (int m = 0; m < 4; ++m) acc2[m] = (f32x4){0.f, 0.f, 0.f, 0.f};
    #pragma unroll
    for (int kc = 0; kc < 4; ++kc) {
        int kb = kc * 32 + l4 * 8;
        bf16x8 b = *(const bf16x8*)(aw2t + (nw + l15) * 128 + kb);
        #pragma unroll
        for (int m = 0; m < 4; ++m) {
            bf16x8 a = *(const bf16x8*)(H + (mh + m * 16 + l15) * 136 + kb);
            acc2[m] = __builtin_amdgcn_mfma_f32_16x16x32_bf16(a, b, acc2[m], 0, 0, 0);
        }
    }
    float b2 = ab2[nw + l15];
    #pragma unroll
    for (int m = 0; m < 4; ++m) {
        int rb = mh + m * 16 + l4 * 4;
        #pragma unroll
        for (int r = 0; r < 4; ++r) {
            int node = nb + rb + r;
            if (node < N_NODESC)
                ctxout[(size_t)node * CTXD + nw + l15] = acc2[m][r] + b2;
        }
    }
}

// ---------------------------------------------------------------------------
// node_pq: P = [x|ctx|pos] @ WP + b1 ; Q = [x|..|pos] @ WQ  -> bf16 [N][128]
// 8 waves: nq2 0,1 -> P cols ; nq2 2,3 -> Q cols (WQ read from global)
// ---------------------------------------------------------------------------
#define PQ_A 0
#define PQ_W 63488
#define PQ_LDS 126976

__global__ __launch_bounds__(512) void node_pq(
    const float* __restrict__ x, const float* __restrict__ ctxb,
    const float* __restrict__ pos,
    const unsigned short* __restrict__ wp, const unsigned short* __restrict__ wq,
    const float* __restrict__ b1,
    unsigned short* __restrict__ Pp, unsigned short* __restrict__ Qq)
{
    extern __shared__ char smem[];
    const int tid = threadIdx.x;
    const int nb = blockIdx.x * 128;

    {
        const int4* src = (const int4*)wp;
        for (int i = tid; i < 3584; i += 512) {
            int n = i / 28, c = i - n * 28;
            *(int4*)(smem + PQ_W + n * 496 + c * 16) = src[i];
        }
    }
    {
        int nl = tid >> 2, part = tid & 3;
        int n = nb + nl; if (n >= N_NODESC) n = N_NODESC - 1;
        unsigned* Aw = (unsigned*)(smem + PQ_A) + nl * 124 + part * 16;
        if (part < 2) {
            const float4* xs = (const float4*)(x + (size_t)n * XD + part * 32);
            #pragma unroll
            for (int q = 0; q < 8; ++q) {
                float4 v = xs[q];
                Aw[2 * q]     = pack2(v.x, v.y);
                Aw[2 * q + 1] = pack2(v.z, v.w);
            }
        } else if (part == 2) {
            const float4* cs = (const float4*)(ctxb + (size_t)n * CTXD);
            #pragma unroll
            for (int q = 0; q < 8; ++q) {
                float4 v = cs[q];
                Aw[2 * q]     = pack2(v.x, v.y);
                Aw[2 * q + 1] = pack2(v.z, v.w);
            }
        } else {
            const float4* cs = (const float4*)(ctxb + (size_t)n * CTXD + 32);
            #pragma unroll
            for (int q = 0; q < 8; ++q) {
                float4 v = cs[q];
                Aw[2 * q]     = pack2(v.x, v.y);
                Aw[2 * q + 1] = pack2(v.z, v.w);
            }
            float2 p2 = *(const float2*)(pos + 2 * (size_t)n);
            Aw[16] = pack2(p2.x, p2.y);
            #pragma unroll
            for (int z = 17; z < 64; ++z) Aw[z] = 0u;
        }
    }
    __syncthreads();

    const int lane = tid & 63, l15 = lane & 15, l4 = lane >> 4;
    const int wave = tid >> 6;
    const int mh = (wave >> 2) * 64;
    const int nq2 = wave & 3;

    f32x4 acc[4][4];
    #pragma unroll
    for (int m = 0; m < 4; ++m)
        #pragma unroll
        for (int n = 0; n < 4; ++n) acc[m][n] = (f32x4){0.f, 0.f, 0.f, 0.f};

    if (nq2 < 2) {
        const int cb = nq2 * 64;
        #pragma unroll
        for (int kc = 0; kc < 7; ++kc) {
            int ko = kc * 64 + l4 * 16;
            bf16x8 b0 = *(const bf16x8*)(smem + PQ_W + (cb + l15) * 496 + ko);
            bf16x8 b1v = *(const bf16x8*)(smem + PQ_W + (cb + 16 + l15) * 496 + ko);
            bf16x8 b2v = *(const bf16x8*)(smem + PQ_W + (cb + 32 + l15) * 496 + ko);
            bf16x8 b3v = *(const bf16x8*)(smem + PQ_W + (cb + 48 + l15) * 496 + ko);
            #pragma unroll
            for (int m = 0; m < 4; ++m) {
                bf16x8 a = *(const bf16x8*)(smem + PQ_A + (mh + m * 16 + l15) * 496 + ko);
                acc[m][0] = __builtin_amdgcn_mfma_f32_16x16x32_bf16(a, b0, acc[m][0], 0, 0, 0);
                acc[m][1] = __builtin_amdgcn_mfma_f32_16x16x32_bf16(a, b1v, acc[m][1], 0, 0, 0);
                acc[m][2] = __builtin_amdgcn_mfma_f32_16x16x32_bf16(a, b2v, acc[m][2], 0, 0, 0);
                acc[m][3] = __builtin_amdgcn_mfma_f32_16x16x32_bf16(a, b3v, acc[m][3], 0, 0, 0);
            }
        }
        #pragma unroll
        for (int nn = 0; nn < 4; ++nn) {
            int col = cb + nn * 16 + l15;
            float bb = b1[col];
            #pragma unroll
            for (int m = 0; m < 4; ++m) {
                int rb = mh + m * 16 + l4 * 4;
                #pragma unroll
                for (int r = 0; r < 4; ++r) {
                    int node = nb + rb + r;
                    if (node < N_NODESC)
                        Pp[(size_t)node * 128 + col] = f2bf(acc[m][nn][r] + bb);
                }
            }
        }
    } else {
        const int cb = (nq2 - 2) * 64;
        const int kcs[3] = {0, 1, 4};
        #pragma unroll
        for (int t = 0; t < 3; ++t) {
            int kc = kcs[t];
            int kb = kc * 32 + l4 * 8;
            bf16x8 b0 = *(const bf16x8*)(wq + (cb + l15) * 224 + kb);
            bf16x8 b1v = *(const bf16x8*)(wq + (cb + 16 + l15) * 224 + kb);
            bf16x8 b2v = *(const bf16x8*)(wq + (cb + 32 + l15) * 224 + kb);
            bf16x8 b3v = *(const bf16x8*)(wq + (cb + 48 + l15) * 224 + kb);
            #pragma unroll
            for (int m = 0; m < 4; ++m) {
                bf16x8 a = *(const bf16x8*)(smem + PQ_A + (mh + m * 16 + l15) * 496 + kb * 2);
                acc[m][0] = __builtin_amdgcn_mfma_f32_16x16x32_bf16(a, b0, acc[m][0], 0, 0, 0);
                acc[m][1] = __builtin_amdgcn_mfma_f32_16x16x32_bf16(a, b1v, acc[m][1], 0, 0, 0);
                acc[m][2] = __builtin_amdgcn_mfma_f32_16x16x32_bf16(a, b2v, acc[m][2], 0, 0, 0);
                acc[m][3] = __builtin_amdgcn_mfma_f32_16x16x32_bf16(a, b3v, acc[m][3], 0, 0, 0);
            }
        }
        #pragma unroll
        for (int nn = 0; nn < 4; ++nn) {
            int col = cb + nn * 16 + l15;
            #pragma unroll
            for (int m = 0; m < 4; ++m) {
                int rb = mh + m * 16 + l4 * 4;
                #pragma unroll
                for (int r = 0; r < 4; ++r) {
                    int node = nb + rb + r;
                    if (node < N_NODESC)
                        Qq[(size_t)node * 128 + col] = f2bf(acc[m][nn][r]);
                }
            }
        }
    }
}

// ---------------------------------------------------------------------------
// L2 edges (sorted): h = relu(P[row] + Q[col]) -> H bf16 ; MFMA K=128 -> 64 ;
// run-merge reduce into sum2.
// ---------------------------------------------------------------------------
__global__ __launch_bounds__(512) void l2_edge(
    const int* __restrict__ er, const int* __restrict__ ec,
    const unsigned short* __restrict__ Pp, const unsigned short* __restrict__ Qq,
    const unsigned short* __restrict__ w2t, float* __restrict__ sum2)
{
    __shared__ unsigned short H[128 * 136];
    __shared__ int rows_s[128];
    const int tid = threadIdx.x;
    const int eb = blockIdx.x * 128;

    if (tid < 128) rows_s[tid] = er[eb + tid];
    {
        int el = tid >> 2, part = tid & 3;
        int e = eb + el;
        int ri = er[e], ci = ec[e];
        const uint4* pr = (const uint4*)(Pp + (size_t)ri * 128 + part * 32);
        const uint4* qr = (const uint4*)(Qq + (size_t)ci * 128 + part * 32);
        unsigned* Hw = (unsigned*)H + el * 68 + part * 16;
        #pragma unroll
        for (int q = 0; q < 4; ++q) {
            uint4 pv = pr[q], qv = qr[q];
            Hw[4 * q + 0] = pack2(fmaxf(bflo(pv.x) + bflo(qv.x), 0.f),
                                  fmaxf(bfhi(pv.x) + bfhi(qv.x), 0.f));
            Hw[4 * q + 1] = pack2(fmaxf(bflo(pv.y) + bflo(qv.y), 0.f),
                                  fmaxf(bfhi(pv.y) + bfhi(qv.y), 0.f));
            Hw[4 * q + 2] = pack2(fmaxf(bflo(pv.z) + bflo(qv.z), 0.f),
                                  fmaxf(bfhi(pv.z) + bfhi(qv.z), 0.f));
            Hw[4 * q + 3] = pack2(fmaxf(bflo(pv.w) + bflo(qv.w), 0.f),
                                  fmaxf(bfhi(pv.w) + bfhi(qv.w), 0.f));
        }
    }
    __syncthreads();

    const int lane = tid & 63, l15 = lane & 15, l4 = lane >> 4;
    const int wave = tid >> 6;
    const int mh = (wave >> 2) * 64;
    const int nw = (wave & 3) * 16;

    f32x4 acc[4];
    #pragma unroll
    for (int m = 0; m < 4; ++m) acc[m] = (f32x4){0.f, 0.f, 0.f, 0.f};

    #pragma unroll
    for (int k = 0; k < 4; ++k) {
        int kb = k * 32 + l4 * 8;
        bf16x8 b = *(const bf16x8*)(w2t + (nw + l15) * 128 + kb);
        #pragma unroll
        for (int m = 0; m < 4; ++m) {
            bf16x8 a = *(const bf16x8*)(H + (mh + m * 16 + l15) * 136 + kb);
            acc[m] = __builtin_amdgcn_mfma_f32_16x16x32_bf16(a, b, acc[m], 0, 0, 0);
        }
    }
    __syncthreads();
    float* S = (float*)H;   // [128][68]
    #pragma unroll
    for (int m = 0; m < 4; ++m) {
        int rb = mh + m * 16 + l4 * 4;
        #pragma unroll
        for (int r = 0; r < 4; ++r)
            S[(rb + r) * 68 + nw + l15] = acc[m][r];
    }
    __syncthreads();
    {
        int c = tid & 63, g = tid >> 6;
        int e0 = g * 16;
        int cur = rows_s[e0];
        float v = S[e0 * 68 + c];
        for (int r = 1; r < 16; ++r) {
            int rr = rows_s[e0 + r];
            float u = S[(e0 + r) * 68 + c];
            if (rr == cur) { v += u; }
            else { unsafeAtomicAdd(sum2 + (size_t)cur * OUTD + c, v); cur = rr; v = u; }
        }
        unsafeAtomicAdd(sum2 + (size_t)cur * OUTD + c, v);
    }
}

// ---------------------------------------------------------------------------
// out = MLP([x, mean(m2)+l2m_b2]) (128 -> 128 -> 64), MFMA
// ---------------------------------------------------------------------------
__global__ __launch_bounds__(512) void out_mfma(
    const float* __restrict__ x, const float* __restrict__ sum2,
    const float* __restrict__ cnt, const float* __restrict__ mb2,
    const unsigned short* __restrict__ bw1t, const float* __restrict__ ab1,
    const unsigned short* __restrict__ bw2t, const float* __restrict__ ab2,
    float* __restrict__ out)
{
    extern __shared__ unsigned short sm[];
    unsigned short* A = sm;              // [128][136]
    unsigned short* H = sm + 128 * 136;  // [128][136]
    const int tid = threadIdx.x;
    const int nb = blockIdx.x * 128;

    {
        int nl = tid >> 2, part = tid & 3;
        int n = nb + nl; if (n >= N_NODESC) n = N_NODESC - 1;
        unsigned* Aw = (unsigned*)A + nl * 68 + part * 16;
        if (part < 2) {
            const float4* xs = (const float4*)(x + (size_t)n * XD + part * 32);
            #pragma unroll
            for (int q = 0; q < 8; ++q) {
                float4 v = xs[q];
                Aw[2 * q]     = pack2(v.x, v.y);
                Aw[2 * q + 1] = pack2(v.z, v.w);
            }
        } else {
            float inv = 1.0f / fmaxf(cnt[n], 1.0f);
            const float4* s = (const float4*)(sum2 + (size_t)n * OUTD + (part - 2) * 32);
            const float4* m = (const float4*)(mb2 + (part - 2) * 32);
            #pragma unroll
            for (int q = 0; q < 8; ++q) {
                float4 v = s[q]; float4 b = m[q];
                Aw[2 * q]     = pack2(fmaf(v.x, inv, b.x), fmaf(v.y, inv, b.y));
                Aw[2 * q + 1] = pack2(fmaf(v.z, inv, b.z), fmaf(v.w, inv, b.w));
            }
        }
    }
    __syncthreads();

    const int lane = tid & 63, l15 = lane & 15, l4 = lane >> 4;
    const int wave = tid >> 6;
    const int mh = (wave >> 2) * 64;
    const int nq = (wave & 3) * 32;

    f32x4 acc[4][2];
    #pragma unroll
    for (int m = 0; m < 4; ++m)
        #pragma unroll
        for (int n = 0; n < 2; ++n) acc[m][n] = (f32x4){0.f, 0.f, 0.f, 0.f};

    #pragma unroll
    for (int kc = 0; kc < 4; ++kc) {
        int kb = kc * 32 + l4 * 8;
        bf16x8 b0 = *(const bf16x8*)(bw1t + (nq + l15) * 128 + kb);
        bf16x8 b1v = *(const bf16x8*)(bw1t + (nq + 16 + l15) * 128 + kb);
        #pragma unroll
        for (int m = 0; m < 4; ++m) {
            bf16x8 a = *(const bf16x8*)(A + (mh + m * 16 + l15) * 136 + kb);
            acc[m][0] = __builtin_amdgcn_mfma_f32_16x16x32_bf16(a, b0, acc[m][0], 0, 0, 0);
            acc[m][1] = __builtin_amdgcn_mfma_f32_16x16x32_bf16(a, b1v, acc[m][1], 0, 0, 0);
        }
    }
    float bv0 = ab1[nq + l15], bv1 = ab1[nq + 16 + l15];
    #pragma unroll
    for (int m = 0; m < 4; ++m) {
        int rb = mh + m * 16 + l4 * 4;
        #pragma unroll
        for (int nn = 0; nn < 2; ++nn) {
            float bv = nn ? bv1 : bv0;
            int col = nq + nn * 16 + l15;
            #pragma unroll
            for (int r = 0; r < 4; ++r)
                H[(rb + r) * 136 + col] = f2bf(fmaxf(acc[m][nn][r] + bv, 0.f));
        }
    }
    __syncthreads();

    const int nw = (wave & 3) * 16;
    f32x4 acc2[4];
    #pragma unroll
    for (int m = 0; m < 4; ++m) acc2[m] = (f32x4){0.f, 0.f, 0.f, 0.f};
    #pragma unroll
    for (int kc = 0; kc < 4; ++kc) {
        int kb = kc * 32 + l4 * 8;
        bf16x8 b = *(const bf16x8*)(bw2t + (nw + l15) * 128 + kb);
        #pragma unroll
        for (int m = 0; m < 4; ++m) {
            bf16x8 a = *(const bf16x8*)(H + (mh + m * 16 + l15) * 136 + kb);
            acc2[m] = __builtin_amdgcn_mfma_f32_16x16x32_bf16(a, b, acc2[m], 0, 0, 0);
        }
    }
    float b2 = ab2[nw + l15];
    #pragma unroll
    for (int m = 0; m < 4; ++m) {
        int rb = mh + m * 16 + l4 * 4;
        #pragma unroll
        for (int r = 0; r < 4; ++r) {
            int node = nb + rb + r;
            if (node < N_NODESC)
                out[(size_t)node * OUTD + nw + l15] = acc2[m][r] + b2;
        }
    }
}

// ---------------------------------------------------------------------------
extern "C" void kernel_launch(void* const* d_in, const int* in_sizes, int n_in,
                              void* d_out, int out_size, void* d_ws, size_t ws_size,
                              hipStream_t stream)
{
    const float* x      = (const float*)d_in[0];
    const float* pos    = (const float*)d_in[1];
    const int*   ei     = (const int*)  d_in[2];
    const float* l1m_w1 = (const float*)d_in[3];
    const float* l1m_b1 = (const float*)d_in[4];
    const float* l1m_w2 = (const float*)d_in[5];
    const float* l1m_b2 = (const float*)d_in[6];
    const float* l1a_w1 = (const float*)d_in[7];
    const float* l1a_b1 = (const float*)d_in[8];
    const float* l1a_w2 = (const float*)d_in[9];
    const float* l1a_b2 = (const float*)d_in[10];
    const float* l2m_w1 = (const float*)d_in[11];
    const float* l2m_b1 = (const float*)d_in[12];
    const float* l2m_w2 = (const float*)d_in[13];
    const float* l2m_b2 = (const float*)d_in[14];
    const float* l2a_w1 = (const float*)d_in[15];
    const float* l2a_b1 = (const float*)d_in[16];
    const float* l2a_w2 = (const float*)d_in[17];
    const float* l2a_b2 = (const float*)d_in[18];

    float* ws    = (float*)d_ws;
    float* sum1  = ws;                                   // [N][64]
    float* sum2  = sum1 + (size_t)N_NODESC * CTXD;       // [N][64]
    float* ctxb  = sum2 + (size_t)N_NODESC * OUTD;       // [N][64]
    float* cnt_f = ctxb + (size_t)N_NODESC * CTXD;       // [NBINS]
    unsigned short* Pp   = (unsigned short*)(cnt_f + NBINS);    // [N][128]
    unsigned short* Qq   = Pp + (size_t)N_NODESC * 128;         // [N][128]
    unsigned short* wp   = Qq + (size_t)N_NODESC * 128;         // 128*224
    unsigned short* wq   = wp + 128 * 224;
    unsigned short* w2t1 = wq + 128 * 224;               // 64*128
    unsigned short* w2t2 = w2t1 + 64 * 128;
    unsigned short* aw1t = w2t2 + 64 * 128;              // 128*64
    unsigned short* aw2t = aw1t + 128 * 64;              // 64*128
    unsigned short* bw1t = aw2t + 64 * 128;              // 128*128
    unsigned short* bw2t = bw1t + 128 * 128;             // 64*128
    int* hist  = (int*)(bw2t + 64 * 128);                // [NBINS]
    int* head  = hist + NBINS;                           // [NBINS]
    int* bsums = head + NBINS;                           // [256]
    int* er    = bsums + 256;                            // [E]
    int* ec    = er + N_EDGESC;                          // [E]

    hipMemsetAsync(d_ws, 0, (size_t)2 * N_NODESC * 64 * sizeof(float), stream);
    hipMemsetAsync(hist, 0, NBINS * sizeof(int), stream);

    hipFuncSetAttribute((const void*)node_pq,
                        hipFuncAttributeMaxDynamicSharedMemorySize, PQ_LDS);
    hipFuncSetAttribute((const void*)out_mfma,
                        hipFuncAttributeMaxDynamicSharedMemorySize, 2 * 128 * 136 * 2);

    hist_k<<<(N_EDGESC + 255) / 256, 256, 0, stream>>>(ei, hist);
    scan_a<<<NBINS / 256, 256, 0, stream>>>(hist, bsums);
    scan_b<<<1, 256, 0, stream>>>(bsums);
    scan_c<<<NBINS / 256, 256, 0, stream>>>(hist, bsums, head, cnt_f);
    scatter_k<<<(N_EDGESC + 255) / 256, 256, 0, stream>>>(ei, head, er, ec);

    prep_weights<<<64, 256, 0, stream>>>(l2m_w1, l2m_w2, l1m_w2,
                                         l1a_w1, l1a_w2, l2a_w1, l2a_w2,
                                         wp, wq, w2t1, w2t2, aw1t, aw2t, bw1t, bw2t);

    l1_mfma<<<N_EDGESC / 128, 512, 0, stream>>>(
        er, ec, pos, l1m_w1, l1m_b1, w2t1, sum1);

    ctx_mfma<<<(N_NODESC + 127) / 128, 512, 0, stream>>>(
        sum1, cnt_f, l1m_b2, aw1t, l1a_b1, aw2t, l1a_b2, ctxb);

    node_pq<<<(N_NODESC + 127) / 128, 512, PQ_LDS, stream>>>(
        x, ctxb, pos, wp, wq, l2m_b1, Pp, Qq);

    l2_edge<<<N_EDGESC / 128, 512, 0, stream>>>(
        er, ec, Pp, Qq, w2t2, sum2);

    out_mfma<<<(N_NODESC + 127) / 128, 512, 2 * 128 * 136 * 2, stream>>>(
        x, sum2, cnt_f, l2m_b2, bw1t, l2a_b1, bw2t, l2a_b2, (float*)d_out);
}

// Round 5
// 333.168 us; speedup vs baseline: 2.5565x; 1.1588x over previous
//
#include <hip/hip_runtime.h>

#define N_NODESC 50000
#define N_EDGESC 800000
#define XD 64
#define HIDD 128
#define CTXD 64
#define OUTD 64
#define NBINS 50176   // 196 * 256

typedef __bf16 bf16x8 __attribute__((ext_vector_type(8)));
typedef float f32x4 __attribute__((ext_vector_type(4)));

__device__ __forceinline__ unsigned short f2bf(float x) {
    __bf16 b = (__bf16)x;                 // RTNE, compiler fuses pairs to v_cvt_pk_bf16_f32
    return __builtin_bit_cast(unsigned short, b);
}
__device__ __forceinline__ unsigned int pack2(float lo, float hi) {
    return (unsigned int)f2bf(lo) | ((unsigned int)f2bf(hi) << 16);
}
__device__ __forceinline__ float bflo(unsigned v) {
    return __builtin_bit_cast(float, v << 16);
}
__device__ __forceinline__ float bfhi(unsigned v) {
    return __builtin_bit_cast(float, v & 0xFFFF0000u);
}

// ---------------------------------------------------------------------------
// Sort: histogram
// ---------------------------------------------------------------------------
__global__ __launch_bounds__(256) void hist_k(const int* __restrict__ ei,
                                              int* __restrict__ hist)
{
    int e = blockIdx.x * 256 + threadIdx.x;
    if (e < N_EDGESC) atomicAdd(&hist[ei[e]], 1);
}

__global__ __launch_bounds__(256) void scan_a(const int* __restrict__ hist,
                                              int* __restrict__ bsums)
{
    __shared__ int ps[256];
    int t = threadIdx.x;
    int v = hist[blockIdx.x * 256 + t];
    ps[t] = v;
    __syncthreads();
    for (int off = 1; off < 256; off <<= 1) {
        int u = (t >= off) ? ps[t - off] : 0;
        __syncthreads();
        ps[t] += u;
        __syncthreads();
    }
    if (t == 255) bsums[blockIdx.x] = ps[255];
}

__global__ __launch_bounds__(256) void scan_b(int* __restrict__ bsums)
{
    __shared__ int ps[256];
    int t = threadIdx.x;
    int v = (t < 196) ? bsums[t] : 0;
    ps[t] = v;
    __syncthreads();
    for (int off = 1; off < 256; off <<= 1) {
        int u = (t >= off) ? ps[t - off] : 0;
        __syncthreads();
        ps[t] += u;
        __syncthreads();
    }
    if (t < 196) bsums[t] = ps[t] - v;   // exclusive
}

__global__ __launch_bounds__(256) void scan_c(const int* __restrict__ hist,
                                              const int* __restrict__ bsums,
                                              int* __restrict__ head,
                                              float* __restrict__ cnt_f)
{
    __shared__ int ps[256];
    int t = threadIdx.x;
    int bin = blockIdx.x * 256 + t;
    int v = hist[bin];
    ps[t] = v;
    __syncthreads();
    for (int off = 1; off < 256; off <<= 1) {
        int u = (t >= off) ? ps[t - off] : 0;
        __syncthreads();
        ps[t] += u;
        __syncthreads();
    }
    head[bin] = ps[t] - v + bsums[blockIdx.x];
    cnt_f[bin] = (float)v;
}

__global__ __launch_bounds__(256) void scatter_k(const int* __restrict__ ei,
                                                 int* __restrict__ head,
                                                 int2* __restrict__ eg)
{
    int e = blockIdx.x * 256 + threadIdx.x;
    if (e >= N_EDGESC) return;
    int row = ei[e];
    int col = ei[N_EDGESC + e];
    int p = atomicAdd(&head[row], 1);
    eg[p] = make_int2(row, col);
}

// ---------------------------------------------------------------------------
// Prep: bf16 weight transposes / combinations (see round-4 notes).
// ---------------------------------------------------------------------------
__global__ void prep_weights(const float* __restrict__ w1,
                             const float* __restrict__ l2m_w2,
                             const float* __restrict__ l1m_w2,
                             const float* __restrict__ l1a_w1,
                             const float* __restrict__ l1a_w2,
                             const float* __restrict__ l2a_w1,
                             const float* __restrict__ l2a_w2,
                             unsigned short* __restrict__ wp,
                             unsigned short* __restrict__ wq,
                             unsigned short* __restrict__ w2t1,
                             unsigned short* __restrict__ w2t2,
                             unsigned short* __restrict__ aw1t,
                             unsigned short* __restrict__ aw2t,
                             unsigned short* __restrict__ bw1t,
                             unsigned short* __restrict__ bw2t)
{
    int i0 = blockIdx.x * 256 + threadIdx.x;
    int stride = gridDim.x * 256;
    for (int idx = i0; idx < 128 * 224; idx += stride) {
        int n = idx / 224, k = idx - n * 224;
        float vp = 0.f, vq = 0.f;
        if (k < 64)        { vp = w1[k * 128 + n] - w1[(64 + k) * 128 + n];
                             vq = w1[(64 + k) * 128 + n]; }
        else if (k < 128)  { vp = w1[(130 + k - 64) * 128 + n]; }
        else if (k < 130)  { vp = -w1[(128 + (k - 128)) * 128 + n];
                             vq =  w1[(128 + (k - 128)) * 128 + n]; }
        wp[idx] = f2bf(vp);
        wq[idx] = f2bf(vq);
    }
    for (int idx = i0; idx < 64 * 128; idx += stride) {
        int n = idx >> 7, k = idx & 127;
        w2t1[idx] = f2bf(l1m_w2[k * 64 + n]);
        w2t2[idx] = f2bf(l2m_w2[k * 64 + n]);
        aw2t[idx] = f2bf(l1a_w2[k * 64 + n]);
        bw2t[idx] = f2bf(l2a_w2[k * 64 + n]);
    }
    for (int idx = i0; idx < 128 * 64; idx += stride) {
        int n = idx >> 6, k = idx & 63;
        aw1t[idx] = f2bf(l1a_w1[k * 128 + n]);
    }
    for (int idx = i0; idx < 128 * 128; idx += stride) {
        int n = idx >> 7, k = idx & 127;
        bw1t[idx] = f2bf(l2a_w1[k * 128 + n]);
    }
}

// ---------------------------------------------------------------------------
// node_u: u[n][128] = pos[n] @ l1m_w1  (bf16)  -- rank-2 GEMV per node
// 4 threads per node, 32 cols each.
// ---------------------------------------------------------------------------
__global__ __launch_bounds__(256) void node_u(const float* __restrict__ pos,
                                              const float* __restrict__ w1,
                                              unsigned short* __restrict__ U)
{
    int t = blockIdx.x * 256 + threadIdx.x;
    int n = t >> 2, part = t & 3;
    if (n >= N_NODESC) return;
    float2 p = *(const float2*)(pos + 2 * (size_t)n);
    const float4* wa = (const float4*)(w1 + part * 32);
    const float4* wb = (const float4*)(w1 + 128 + part * 32);
    unsigned* Uw = (unsigned*)U + (size_t)n * 64 + part * 16;
    #pragma unroll
    for (int q = 0; q < 8; ++q) {
        float4 a = wa[q], b = wb[q];
        float h0 = fmaf(p.x, a.x, p.y * b.x);
        float h1 = fmaf(p.x, a.y, p.y * b.y);
        float h2 = fmaf(p.x, a.z, p.y * b.z);
        float h3 = fmaf(p.x, a.w, p.y * b.w);
        Uw[2 * q]     = pack2(h0, h1);
        Uw[2 * q + 1] = pack2(h2, h3);
    }
}

// ---------------------------------------------------------------------------
// L1 edges (sorted): h = relu(u[col]-u[row]+b1) -> H bf16 ; MFMA K=128 -> 64 ;
// run-merge reduce into sum1.
// ---------------------------------------------------------------------------
__global__ __launch_bounds__(512) void l1_edge(
    const int2* __restrict__ eg,
    const unsigned short* __restrict__ U, const float* __restrict__ b1,
    const unsigned short* __restrict__ w2t, float* __restrict__ sum1)
{
    __shared__ unsigned short H[128 * 136];
    __shared__ int rows_s[128];
    const int tid = threadIdx.x;
    const int eb = blockIdx.x * 128;

    {
        int el = tid >> 2, part = tid & 3;
        int2 rc = eg[eb + el];
        if (part == 0) rows_s[el] = rc.x;
        const uint4* ur = (const uint4*)(U + (size_t)rc.x * 128 + part * 32);
        const uint4* uc = (const uint4*)(U + (size_t)rc.y * 128 + part * 32);
        const float4* bb = (const float4*)(b1 + part * 32);
        uint4* Hw = (uint4*)((unsigned*)H + el * 68 + part * 16);
        #pragma unroll
        for (int q = 0; q < 4; ++q) {
            uint4 rv = ur[q], cv = uc[q];
            float4 f0 = bb[2 * q], f1 = bb[2 * q + 1];
            unsigned w0 = pack2(fmaxf(bflo(cv.x) - bflo(rv.x) + f0.x, 0.f),
                                fmaxf(bfhi(cv.x) - bfhi(rv.x) + f0.y, 0.f));
            unsigned w1v = pack2(fmaxf(bflo(cv.y) - bflo(rv.y) + f0.z, 0.f),
                                 fmaxf(bfhi(cv.y) - bfhi(rv.y) + f0.w, 0.f));
            unsigned w2 = pack2(fmaxf(bflo(cv.z) - bflo(rv.z) + f1.x, 0.f),
                                fmaxf(bfhi(cv.z) - bfhi(rv.z) + f1.y, 0.f));
            unsigned w3 = pack2(fmaxf(bflo(cv.w) - bflo(rv.w) + f1.z, 0.f),
                                fmaxf(bfhi(cv.w) - bfhi(rv.w) + f1.w, 0.f));
            Hw[q] = make_uint4(w0, w1v, w2, w3);
        }
    }
    __syncthreads();

    const int lane = tid & 63, l15 = lane & 15, l4 = lane >> 4;
    const int wave = tid >> 6;
    const int mh = (wave >> 2) * 64;
    const int nw = (wave & 3) * 16;

    f32x4 acc[4];
    #pragma unroll
    for (int m = 0; m < 4; ++m) acc[m] = (f32x4){0.f, 0.f, 0.f, 0.f};

    #pragma unroll
    for (int k = 0; k < 4; ++k) {
        int kb = k * 32 + l4 * 8;
        bf16x8 b = *(const bf16x8*)(w2t + (nw + l15) * 128 + kb);
        #pragma unroll
        for (int m = 0; m < 4; ++m) {
            bf16x8 a = *(const bf16x8*)(H + (mh + m * 16 + l15) * 136 + kb);
            acc[m] = __builtin_amdgcn_mfma_f32_16x16x32_bf16(a, b, acc[m], 0, 0, 0);
        }
    }
    __syncthreads();
    float* S = (float*)H;   // [128][68]
    #pragma unroll
    for (int m = 0; m < 4; ++m) {
        int rb = mh + m * 16 + l4 * 4;
        #pragma unroll
        for (int r = 0; r < 4; ++r)
            S[(rb + r) * 68 + nw + l15] = acc[m][r];
    }
    __syncthreads();
    {
        int c = tid & 63, g = tid >> 6;
        int e0 = g * 16;
        float sv[16];
        int rw[16];
        #pragma unroll
        for (int r = 0; r < 16; ++r) {
            sv[r] = S[(e0 + r) * 68 + c];
            rw[r] = rows_s[e0 + r];
        }
        int cur = rw[0];
        float v = sv[0];
        #pragma unroll
        for (int r = 1; r < 16; ++r) {
            if (rw[r] == cur) { v += sv[r]; }
            else { unsafeAtomicAdd(sum1 + (size_t)cur * CTXD + c, v); cur = rw[r]; v = sv[r]; }
        }
        unsafeAtomicAdd(sum1 + (size_t)cur * CTXD + c, v);
    }
}

// ---------------------------------------------------------------------------
// ctx = MLP(mean(m1)+l1m_b2)  (64 -> 128 -> 64), MFMA, 128 nodes/block
// ---------------------------------------------------------------------------
__global__ __launch_bounds__(512) void ctx_mfma(
    const float* __restrict__ sum1, const float* __restrict__ cnt,
    const float* __restrict__ mb2,
    const unsigned short* __restrict__ aw1t, const float* __restrict__ ab1,
    const unsigned short* __restrict__ aw2t, const float* __restrict__ ab2,
    float* __restrict__ ctxout)
{
    __shared__ unsigned short A[128 * 72];
    __shared__ unsigned short H[128 * 136];
    const int tid = threadIdx.x;
    const int nb = blockIdx.x * 128;

    {
        int nl = tid >> 2, part = tid & 3;
        int n = nb + nl; if (n >= N_NODESC) n = N_NODESC - 1;
        float inv = 1.0f / fmaxf(cnt[n], 1.0f);
        const float4* s = (const float4*)(sum1 + (size_t)n * CTXD + part * 16);
        const float4* m = (const float4*)(mb2 + part * 16);
        unsigned* Aw = (unsigned*)A + nl * 36 + part * 8;
        #pragma unroll
        for (int q = 0; q < 4; ++q) {
            float4 v = s[q]; float4 b = m[q];
            Aw[2 * q]     = pack2(fmaf(v.x, inv, b.x), fmaf(v.y, inv, b.y));
            Aw[2 * q + 1] = pack2(fmaf(v.z, inv, b.z), fmaf(v.w, inv, b.w));
        }
    }
    __syncthreads();

    const int lane = tid & 63, l15 = lane & 15, l4 = lane >> 4;
    const int wave = tid >> 6;
    const int mh = (wave >> 2) * 64;
    const int nq = (wave & 3) * 32;

    f32x4 acc[4][2];
    #pragma unroll
    for (int m = 0; m < 4; ++m)
        #pragma unroll
        for (int n = 0; n < 2; ++n) acc[m][n] = (f32x4){0.f, 0.f, 0.f, 0.f};

    #pragma unroll
    for (int kc = 0; kc < 2; ++kc) {
        int kb = kc * 32 + l4 * 8;
        bf16x8 b0 = *(const bf16x8*)(aw1t + (nq + l15) * 64 + kb);
        bf16x8 b1v = *(const bf16x8*)(aw1t + (nq + 16 + l15) * 64 + kb);
        #pragma unroll
        for (int m = 0; m < 4; ++m) {
            bf16x8 a = *(const bf16x8*)(A + (mh + m * 16 + l15) * 72 + kb);
            acc[m][0] = __builtin_amdgcn_mfma_f32_16x16x32_bf16(a, b0, acc[m][0], 0, 0, 0);
            acc[m][1] = __builtin_amdgcn_mfma_f32_16x16x32_bf16(a, b1v, acc[m][1], 0, 0, 0);
        }
    }
    float bv0 = ab1[nq + l15], bv1 = ab1[nq + 16 + l15];
    #pragma unroll
    for (int m = 0; m < 4; ++m) {
        int rb = mh + m * 16 + l4 * 4;
        #pragma unroll
        for (int nn = 0; nn < 2; ++nn) {
            float bv = nn ? bv1 : bv0;
            int col = nq + nn * 16 + l15;
            #pragma unroll
            for (int r = 0; r < 4; ++r)
                H[(rb + r) * 136 + col] = f2bf(fmaxf(acc[m][nn][r] + bv, 0.f));
        }
    }
    __syncthreads();

    const int nw = (wave & 3) * 16;
    f32x4 acc2[4];
    #pragma unroll
    for (int m = 0; m < 4; ++m) acc2[m] = (f32x4){0.f, 0.f, 0.f, 0.f};
    #pragma unroll
    for (int kc = 0; kc < 4; ++kc) {
        int kb = kc * 32 + l4 * 8;
        bf16x8 b = *(const bf16x8*)(aw2t + (nw + l15) * 128 + kb);
        #pragma unroll
        for (int m = 0; m < 4; ++m) {
            bf16x8 a = *(const bf16x8*)(H + (mh + m * 16 + l15) * 136 + kb);
            acc2[m] = __builtin_amdgcn_mfma_f32_16x16x32_bf16(a, b, acc2[m], 0, 0, 0);
        }
    }
    float b2 = ab2[nw + l15];
    #pragma unroll
    for (int m = 0; m < 4; ++m) {
        int rb = mh + m * 16 + l4 * 4;
        #pragma unroll
        for (int r = 0; r < 4; ++r) {
            int node = nb + rb + r;
            if (node < N_NODESC)
                ctxout[(size_t)node * CTXD + nw + l15] = acc2[m][r] + b2;
        }
    }
}

// ---------------------------------------------------------------------------
// node_pq: P = [x|ctx|pos] @ WP + b1 ; Q = [x|..|pos] @ WQ  -> bf16 [N][128]
// ---------------------------------------------------------------------------
#define PQ_A 0
#define PQ_W 63488
#define PQ_LDS 126976

__global__ __launch_bounds__(512) void node_pq(
    const float* __restrict__ x, const float* __restrict__ ctxb,
    const float* __restrict__ pos,
    const unsigned short* __restrict__ wp, const unsigned short* __restrict__ wq,
    const float* __restrict__ b1,
    unsigned short* __restrict__ Pp, unsigned short* __restrict__ Qq)
{
    extern __shared__ char smem[];
    const int tid = threadIdx.x;
    const int nb = blockIdx.x * 128;

    {
        const int4* src = (const int4*)wp;
        for (int i = tid; i < 3584; i += 512) {
            int n = i / 28, c = i - n * 28;
            *(int4*)(smem + PQ_W + n * 496 + c * 16) = src[i];
        }
    }
    {
        int nl = tid >> 2, part = tid & 3;
        int n = nb + nl; if (n >= N_NODESC) n = N_NODESC - 1;
        unsigned* Aw = (unsigned*)(smem + PQ_A) + nl * 124 + part * 16;
        if (part < 2) {
            const float4* xs = (const float4*)(x + (size_t)n * XD + part * 32);
            #pragma unroll
            for (int q = 0; q < 8; ++q) {
                float4 v = xs[q];
                Aw[2 * q]     = pack2(v.x, v.y);
                Aw[2 * q + 1] = pack2(v.z, v.w);
            }
        } else if (part == 2) {
            const float4* cs = (const float4*)(ctxb + (size_t)n * CTXD);
            #pragma unroll
            for (int q = 0; q < 8; ++q) {
                float4 v = cs[q];
                Aw[2 * q]     = pack2(v.x, v.y);
                Aw[2 * q + 1] = pack2(v.z, v.w);
            }
        } else {
            const float4* cs = (const float4*)(ctxb + (size_t)n * CTXD + 32);
            #pragma unroll
            for (int q = 0; q < 8; ++q) {
                float4 v = cs[q];
                Aw[2 * q]     = pack2(v.x, v.y);
                Aw[2 * q + 1] = pack2(v.z, v.w);
            }
            float2 p2 = *(const float2*)(pos + 2 * (size_t)n);
            Aw[16] = pack2(p2.x, p2.y);
            #pragma unroll
            for (int z = 17; z < 64; ++z) Aw[z] = 0u;
        }
    }
    __syncthreads();

    const int lane = tid & 63, l15 = lane & 15, l4 = lane >> 4;
    const int wave = tid >> 6;
    const int mh = (wave >> 2) * 64;
    const int nq2 = wave & 3;

    f32x4 acc[4][4];
    #pragma unroll
    for (int m = 0; m < 4; ++m)
        #pragma unroll
        for (int n = 0; n < 4; ++n) acc[m][n] = (f32x4){0.f, 0.f, 0.f, 0.f};

    if (nq2 < 2) {
        const int cb = nq2 * 64;
        #pragma unroll
        for (int kc = 0; kc < 7; ++kc) {
            int ko = kc * 64 + l4 * 16;
            bf16x8 b0 = *(const bf16x8*)(smem + PQ_W + (cb + l15) * 496 + ko);
            bf16x8 b1v = *(const bf16x8*)(smem + PQ_W + (cb + 16 + l15) * 496 + ko);
            bf16x8 b2v = *(const bf16x8*)(smem + PQ_W + (cb + 32 + l15) * 496 + ko);
            bf16x8 b3v = *(const bf16x8*)(smem + PQ_W + (cb + 48 + l15) * 496 + ko);
            #pragma unroll
            for (int m = 0; m < 4; ++m) {
                bf16x8 a = *(const bf16x8*)(smem + PQ_A + (mh + m * 16 + l15) * 496 + ko);
                acc[m][0] = __builtin_amdgcn_mfma_f32_16x16x32_bf16(a, b0, acc[m][0], 0, 0, 0);
                acc[m][1] = __builtin_amdgcn_mfma_f32_16x16x32_bf16(a, b1v, acc[m][1], 0, 0, 0);
                acc[m][2] = __builtin_amdgcn_mfma_f32_16x16x32_bf16(a, b2v, acc[m][2], 0, 0, 0);
                acc[m][3] = __builtin_amdgcn_mfma_f32_16x16x32_bf16(a, b3v, acc[m][3], 0, 0, 0);
            }
        }
        #pragma unroll
        for (int nn = 0; nn < 4; ++nn) {
            int col = cb + nn * 16 + l15;
            float bb = b1[col];
            #pragma unroll
            for (int m = 0; m < 4; ++m) {
                int rb = mh + m * 16 + l4 * 4;
                #pragma unroll
                for (int r = 0; r < 4; ++r) {
                    int node = nb + rb + r;
                    if (node < N_NODESC)
                        Pp[(size_t)node * 128 + col] = f2bf(acc[m][nn][r] + bb);
                }
            }
        }
    } else {
        const int cb = (nq2 - 2) * 64;
        const int kcs[3] = {0, 1, 4};
        #pragma unroll
        for (int t = 0; t < 3; ++t) {
            int kc = kcs[t];
            int kb = kc * 32 + l4 * 8;
            bf16x8 b0 = *(const bf16x8*)(wq + (cb + l15) * 224 + kb);
            bf16x8 b1v = *(const bf16x8*)(wq + (cb + 16 + l15) * 224 + kb);
            bf16x8 b2v = *(const bf16x8*)(wq + (cb + 32 + l15) * 224 + kb);
            bf16x8 b3v = *(const bf16x8*)(wq + (cb + 48 + l15) * 224 + kb);
            #pragma unroll
            for (int m = 0; m < 4; ++m) {
                bf16x8 a = *(const bf16x8*)(smem + PQ_A + (mh + m * 16 + l15) * 496 + kb * 2);
                acc[m][0] = __builtin_amdgcn_mfma_f32_16x16x32_bf16(a, b0, acc[m][0], 0, 0, 0);
                acc[m][1] = __builtin_amdgcn_mfma_f32_16x16x32_bf16(a, b1v, acc[m][1], 0, 0, 0);
                acc[m][2] = __builtin_amdgcn_mfma_f32_16x16x32_bf16(a, b2v, acc[m][2], 0, 0, 0);
                acc[m][3] = __builtin_amdgcn_mfma_f32_16x16x32_bf16(a, b3v, acc[m][3], 0, 0, 0);
            }
        }
        #pragma unroll
        for (int nn = 0; nn < 4; ++nn) {
            int col = cb + nn * 16 + l15;
            #pragma unroll
            for (int m = 0; m < 4; ++m) {
                int rb = mh + m * 16 + l4 * 4;
                #pragma unroll
                for (int r = 0; r < 4; ++r) {
                    int node = nb + rb + r;
                    if (node < N_NODESC)
                        Qq[(size_t)node * 128 + col] = f2bf(acc[m][nn][r]);
                }
            }
        }
    }
}

// ---------------------------------------------------------------------------
// L2 edges (sorted): h = relu(P[row] + Q[col]) -> H bf16 ; MFMA K=128 -> 64 ;
// run-merge reduce into sum2.
// ---------------------------------------------------------------------------
__global__ __launch_bounds__(512) void l2_edge(
    const int2* __restrict__ eg,
    const unsigned short* __restrict__ Pp, const unsigned short* __restrict__ Qq,
    const unsigned short* __restrict__ w2t, float* __restrict__ sum2)
{
    __shared__ unsigned short H[128 * 136];
    __shared__ int rows_s[128];
    const int tid = threadIdx.x;
    const int eb = blockIdx.x * 128;

    {
        int el = tid >> 2, part = tid & 3;
        int2 rc = eg[eb + el];
        if (part == 0) rows_s[el] = rc.x;
        const uint4* pr = (const uint4*)(Pp + (size_t)rc.x * 128 + part * 32);
        const uint4* qr = (const uint4*)(Qq + (size_t)rc.y * 128 + part * 32);
        uint4* Hw = (uint4*)((unsigned*)H + el * 68 + part * 16);
        #pragma unroll
        for (int q = 0; q < 4; ++q) {
            uint4 pv = pr[q], qv = qr[q];
            unsigned w0 = pack2(fmaxf(bflo(pv.x) + bflo(qv.x), 0.f),
                                fmaxf(bfhi(pv.x) + bfhi(qv.x), 0.f));
            unsigned w1v = pack2(fmaxf(bflo(pv.y) + bflo(qv.y), 0.f),
                                 fmaxf(bfhi(pv.y) + bfhi(qv.y), 0.f));
            unsigned w2 = pack2(fmaxf(bflo(pv.z) + bflo(qv.z), 0.f),
                                fmaxf(bfhi(pv.z) + bfhi(qv.z), 0.f));
            unsigned w3 = pack2(fmaxf(bflo(pv.w) + bflo(qv.w), 0.f),
                                fmaxf(bfhi(pv.w) + bfhi(qv.w), 0.f));
            Hw[q] = make_uint4(w0, w1v, w2, w3);
        }
    }
    __syncthreads();

    const int lane = tid & 63, l15 = lane & 15, l4 = lane >> 4;
    const int wave = tid >> 6;
    const int mh = (wave >> 2) * 64;
    const int nw = (wave & 3) * 16;

    f32x4 acc[4];
    #pragma unroll
    for (int m = 0; m < 4; ++m) acc[m] = (f32x4){0.f, 0.f, 0.f, 0.f};

    #pragma unroll
    for (int k = 0; k < 4; ++k) {
        int kb = k * 32 + l4 * 8;
        bf16x8 b = *(const bf16x8*)(w2t + (nw + l15) * 128 + kb);
        #pragma unroll
        for (int m = 0; m < 4; ++m) {
            bf16x8 a = *(const bf16x8*)(H + (mh + m * 16 + l15) * 136 + kb);
            acc[m] = __builtin_amdgcn_mfma_f32_16x16x32_bf16(a, b, acc[m], 0, 0, 0);
        }
    }
    __syncthreads();
    float* S = (float*)H;   // [128][68]
    #pragma unroll
    for (int m = 0; m < 4; ++m) {
        int rb = mh + m * 16 + l4 * 4;
        #pragma unroll
        for (int r = 0; r < 4; ++r)
            S[(rb + r) * 68 + nw + l15] = acc[m][r];
    }
    __syncthreads();
    {
        int c = tid & 63, g = tid >> 6;
        int e0 = g * 16;
        float sv[16];
        int rw[16];
        #pragma unroll
        for (int r = 0; r < 16; ++r) {
            sv[r] = S[(e0 + r) * 68 + c];
            rw[r] = rows_s[e0 + r];
        }
        int cur = rw[0];
        float v = sv[0];
        #pragma unroll
        for (int r = 1; r < 16; ++r) {
            if (rw[r] == cur) { v += sv[r]; }
            else { unsafeAtomicAdd(sum2 + (size_t)cur * OUTD + c, v); cur = rw[r]; v = sv[r]; }
        }
        unsafeAtomicAdd(sum2 + (size_t)cur * OUTD + c, v);
    }
}

// ---------------------------------------------------------------------------
// out = MLP([x, mean(m2)+l2m_b2]) (128 -> 128 -> 64), MFMA
// ---------------------------------------------------------------------------
__global__ __launch_bounds__(512) void out_mfma(
    const float* __restrict__ x, const float* __restrict__ sum2,
    const float* __restrict__ cnt, const float* __restrict__ mb2,
    const unsigned short* __restrict__ bw1t, const float* __restrict__ ab1,
    const unsigned short* __restrict__ bw2t, const float* __restrict__ ab2,
    float* __restrict__ out)
{
    extern __shared__ unsigned short sm[];
    unsigned short* A = sm;              // [128][136]
    unsigned short* H = sm + 128 * 136;  // [128][136]
    const int tid = threadIdx.x;
    const int nb = blockIdx.x * 128;

    {
        int nl = tid >> 2, part = tid & 3;
        int n = nb + nl; if (n >= N_NODESC) n = N_NODESC - 1;
        unsigned* Aw = (unsigned*)A + nl * 68 + part * 16;
        if (part < 2) {
            const float4* xs = (const float4*)(x + (size_t)n * XD + part * 32);
            #pragma unroll
            for (int q = 0; q < 8; ++q) {
                float4 v = xs[q];
                Aw[2 * q]     = pack2(v.x, v.y);
                Aw[2 * q + 1] = pack2(v.z, v.w);
            }
        } else {
            float inv = 1.0f / fmaxf(cnt[n], 1.0f);
            const float4* s = (const float4*)(sum2 + (size_t)n * OUTD + (part - 2) * 32);
            const float4* m = (const float4*)(mb2 + (part - 2) * 32);
            #pragma unroll
            for (int q = 0; q < 8; ++q) {
                float4 v = s[q]; float4 b = m[q];
                Aw[2 * q]     = pack2(fmaf(v.x, inv, b.x), fmaf(v.y, inv, b.y));
                Aw[2 * q + 1] = pack2(fmaf(v.z, inv, b.z), fmaf(v.w, inv, b.w));
            }
        }
    }
    __syncthreads();

    const int lane = tid & 63, l15 = lane & 15, l4 = lane >> 4;
    const int wave = tid >> 6;
    const int mh = (wave >> 2) * 64;
    const int nq = (wave & 3) * 32;

    f32x4 acc[4][2];
    #pragma unroll
    for (int m = 0; m < 4; ++m)
        #pragma unroll
        for (int n = 0; n < 2; ++n) acc[m][n] = (f32x4){0.f, 0.f, 0.f, 0.f};

    #pragma unroll
    for (int kc = 0; kc < 4; ++kc) {
        int kb = kc * 32 + l4 * 8;
        bf16x8 b0 = *(const bf16x8*)(bw1t + (nq + l15) * 128 + kb);
        bf16x8 b1v = *(const bf16x8*)(bw1t + (nq + 16 + l15) * 128 + kb);
        #pragma unroll
        for (int m = 0; m < 4; ++m) {
            bf16x8 a = *(const bf16x8*)(A + (mh + m * 16 + l15) * 136 + kb);
            acc[m][0] = __builtin_amdgcn_mfma_f32_16x16x32_bf16(a, b0, acc[m][0], 0, 0, 0);
            acc[m][1] = __builtin_amdgcn_mfma_f32_16x16x32_bf16(a, b1v, acc[m][1], 0, 0, 0);
        }
    }
    float bv0 = ab1[nq + l15], bv1 = ab1[nq + 16 + l15];
    #pragma unroll
    for (int m = 0; m < 4; ++m) {
        int rb = mh + m * 16 + l4 * 4;
        #pragma unroll
        for (int nn = 0; nn < 2; ++nn) {
            float bv = nn ? bv1 : bv0;
            int col = nq + nn * 16 + l15;
            #pragma unroll
            for (int r = 0; r < 4; ++r)
                H[(rb + r) * 136 + col] = f2bf(fmaxf(acc[m][nn][r] + bv, 0.f));
        }
    }
    __syncthreads();

    const int nw = (wave & 3) * 16;
    f32x4 acc2[4];
    #pragma unroll
    for (int m = 0; m < 4; ++m) acc2[m] = (f32x4){0.f, 0.f, 0.f, 0.f};
    #pragma unroll
    for (int kc = 0; kc < 4; ++kc) {
        int kb = kc * 32 + l4 * 8;
        bf16x8 b = *(const bf16x8*)(bw2t + (nw + l15) * 128 + kb);
        #pragma unroll
        for (int m = 0; m < 4; ++m) {
            bf16x8 a = *(const bf16x8*)(H + (mh + m * 16 + l15) * 136 + kb);
            acc2[m] = __builtin_amdgcn_mfma_f32_16x16x32_bf16(a, b, acc2[m], 0, 0, 0);
        }
    }
    float b2 = ab2[nw + l15];
    #pragma unroll
    for (int m = 0; m < 4; ++m) {
        int rb = mh + m * 16 + l4 * 4;
        #pragma unroll
        for (int r = 0; r < 4; ++r) {
            int node = nb + rb + r;
            if (node < N_NODESC)
                out[(size_t)node * OUTD + nw + l15] = acc2[m][r] + b2;
        }
    }
}

// ---------------------------------------------------------------------------
extern "C" void kernel_launch(void* const* d_in, const int* in_sizes, int n_in,
                              void* d_out, int out_size, void* d_ws, size_t ws_size,
                              hipStream_t stream)
{
    const float* x      = (const float*)d_in[0];
    const float* pos    = (const float*)d_in[1];
    const int*   ei     = (const int*)  d_in[2];
    const float* l1m_w1 = (const float*)d_in[3];
    const float* l1m_b1 = (const float*)d_in[4];
    const float* l1m_w2 = (const float*)d_in[5];
    const float* l1m_b2 = (const float*)d_in[6];
    const float* l1a_w1 = (const float*)d_in[7];
    const float* l1a_b1 = (const float*)d_in[8];
    const float* l1a_w2 = (const float*)d_in[9];
    const float* l1a_b2 = (const float*)d_in[10];
    const float* l2m_w1 = (const float*)d_in[11];
    const float* l2m_b1 = (const float*)d_in[12];
    const float* l2m_w2 = (const float*)d_in[13];
    const float* l2m_b2 = (const float*)d_in[14];
    const float* l2a_w1 = (const float*)d_in[15];
    const float* l2a_b1 = (const float*)d_in[16];
    const float* l2a_w2 = (const float*)d_in[17];
    const float* l2a_b2 = (const float*)d_in[18];

    float* ws    = (float*)d_ws;
    float* sum1  = ws;                                   // [N][64]
    float* sum2  = sum1 + (size_t)N_NODESC * CTXD;       // [N][64]
    float* ctxb  = sum2 + (size_t)N_NODESC * OUTD;       // [N][64]
    float* cnt_f = ctxb + (size_t)N_NODESC * CTXD;       // [NBINS]
    unsigned short* Pp   = (unsigned short*)(cnt_f + NBINS);    // [N][128]
    unsigned short* Qq   = Pp + (size_t)N_NODESC * 128;         // [N][128]
    unsigned short* U    = Pp;   // aliases Pp: U dead before node_pq writes Pp
    unsigned short* wp   = Qq + (size_t)N_NODESC * 128;         // 128*224
    unsigned short* wq   = wp + 128 * 224;
    unsigned short* w2t1 = wq + 128 * 224;               // 64*128
    unsigned short* w2t2 = w2t1 + 64 * 128;
    unsigned short* aw1t = w2t2 + 64 * 128;              // 128*64
    unsigned short* aw2t = aw1t + 128 * 64;              // 64*128
    unsigned short* bw1t = aw2t + 64 * 128;              // 128*128
    unsigned short* bw2t = bw1t + 128 * 128;             // 64*128
    int* hist  = (int*)(bw2t + 64 * 128);                // [NBINS]
    int* head  = hist + NBINS;                           // [NBINS]
    int* bsums = head + NBINS;                           // [256]
    int2* eg   = (int2*)(bsums + 256);                   // [E]

    hipMemsetAsync(d_ws, 0, (size_t)2 * N_NODESC * 64 * sizeof(float), stream);
    hipMemsetAsync(hist, 0, NBINS * sizeof(int), stream);

    hipFuncSetAttribute((const void*)node_pq,
                        hipFuncAttributeMaxDynamicSharedMemorySize, PQ_LDS);
    hipFuncSetAttribute((const void*)out_mfma,
                        hipFuncAttributeMaxDynamicSharedMemorySize, 2 * 128 * 136 * 2);

    hist_k<<<(N_EDGESC + 255) / 256, 256, 0, stream>>>(ei, hist);
    scan_a<<<NBINS / 256, 256, 0, stream>>>(hist, bsums);
    scan_b<<<1, 256, 0, stream>>>(bsums);
    scan_c<<<NBINS / 256, 256, 0, stream>>>(hist, bsums, head, cnt_f);
    scatter_k<<<(N_EDGESC + 255) / 256, 256, 0, stream>>>(ei, head, eg);

    prep_weights<<<64, 256, 0, stream>>>(l2m_w1, l2m_w2, l1m_w2,
                                         l1a_w1, l1a_w2, l2a_w1, l2a_w2,
                                         wp, wq, w2t1, w2t2, aw1t, aw2t, bw1t, bw2t);

    node_u<<<(N_NODESC * 4 + 255) / 256, 256, 0, stream>>>(pos, l1m_w1, U);

    l1_edge<<<N_EDGESC / 128, 512, 0, stream>>>(eg, U, l1m_b1, w2t1, sum1);

    ctx_mfma<<<(N_NODESC + 127) / 128, 512, 0, stream>>>(
        sum1, cnt_f, l1m_b2, aw1t, l1a_b1, aw2t, l1a_b2, ctxb);

    node_pq<<<(N_NODESC + 127) / 128, 512, PQ_LDS, stream>>>(
        x, ctxb, pos, wp, wq, l2m_b1, Pp, Qq);

    l2_edge<<<N_EDGESC / 128, 512, 0, stream>>>(eg, Pp, Qq, w2t2, sum2);

    out_mfma<<<(N_NODESC + 127) / 128, 512, 2 * 128 * 136 * 2, stream>>>(
        x, sum2, cnt_f, l2m_b2, bw1t, l2a_b1, bw2t, l2a_b2, (float*)d_out);
}

// Round 6
// 306.431 us; speedup vs baseline: 2.7795x; 1.0873x over previous
//
#include <hip/hip_runtime.h>

#define N_NODESC 50000
#define N_EDGESC 800000
#define XD 64
#define HIDD 128
#define CTXD 64
#define OUTD 64
#define NBINS 50176   // 196 * 256
#define TILES 5       // 6250 tiles of 128 edges = 1250 blocks * 5

typedef __bf16 bf16x8 __attribute__((ext_vector_type(8)));
typedef float f32x4 __attribute__((ext_vector_type(4)));

__device__ __forceinline__ unsigned short f2bf(float x) {
    __bf16 b = (__bf16)x;
    return __builtin_bit_cast(unsigned short, b);
}
__device__ __forceinline__ unsigned int pack2(float lo, float hi) {
    return (unsigned int)f2bf(lo) | ((unsigned int)f2bf(hi) << 16);
}
__device__ __forceinline__ float bflo(unsigned v) {
    return __builtin_bit_cast(float, v << 16);
}
__device__ __forceinline__ float bfhi(unsigned v) {
    return __builtin_bit_cast(float, v & 0xFFFF0000u);
}

// lgkm-only barrier: leaves staged global loads (vmcnt) in flight
#define LBARRIER() asm volatile("s_waitcnt lgkmcnt(0)\ns_barrier" ::: "memory")

// ---------------------------------------------------------------------------
// Sort: histogram + hierarchical scan + scatter
// ---------------------------------------------------------------------------
__global__ __launch_bounds__(256) void hist_k(const int* __restrict__ ei,
                                              int* __restrict__ hist)
{
    int e = blockIdx.x * 256 + threadIdx.x;
    if (e < N_EDGESC) atomicAdd(&hist[ei[e]], 1);
}

__global__ __launch_bounds__(256) void scan_a(const int* __restrict__ hist,
                                              int* __restrict__ bsums)
{
    __shared__ int ps[256];
    int t = threadIdx.x;
    int v = hist[blockIdx.x * 256 + t];
    ps[t] = v;
    __syncthreads();
    for (int off = 1; off < 256; off <<= 1) {
        int u = (t >= off) ? ps[t - off] : 0;
        __syncthreads();
        ps[t] += u;
        __syncthreads();
    }
    if (t == 255) bsums[blockIdx.x] = ps[255];
}

__global__ __launch_bounds__(256) void scan_b(int* __restrict__ bsums)
{
    __shared__ int ps[256];
    int t = threadIdx.x;
    int v = (t < 196) ? bsums[t] : 0;
    ps[t] = v;
    __syncthreads();
    for (int off = 1; off < 256; off <<= 1) {
        int u = (t >= off) ? ps[t - off] : 0;
        __syncthreads();
        ps[t] += u;
        __syncthreads();
    }
    if (t < 196) bsums[t] = ps[t] - v;   // exclusive
}

__global__ __launch_bounds__(256) void scan_c(const int* __restrict__ hist,
                                              const int* __restrict__ bsums,
                                              int* __restrict__ head,
                                              float* __restrict__ cnt_f)
{
    __shared__ int ps[256];
    int t = threadIdx.x;
    int bin = blockIdx.x * 256 + t;
    int v = hist[bin];
    ps[t] = v;
    __syncthreads();
    for (int off = 1; off < 256; off <<= 1) {
        int u = (t >= off) ? ps[t - off] : 0;
        __syncthreads();
        ps[t] += u;
        __syncthreads();
    }
    head[bin] = ps[t] - v + bsums[blockIdx.x];
    cnt_f[bin] = (float)v;
}

__global__ __launch_bounds__(256) void scatter_k(const int* __restrict__ ei,
                                                 int* __restrict__ head,
                                                 int2* __restrict__ eg)
{
    int e = blockIdx.x * 256 + threadIdx.x;
    if (e >= N_EDGESC) return;
    int row = ei[e];
    int col = ei[N_EDGESC + e];
    int p = atomicAdd(&head[row], 1);
    eg[p] = make_int2(row, col);
}

// ---------------------------------------------------------------------------
// Prep: bf16 weight transposes / combinations.
// ---------------------------------------------------------------------------
__global__ void prep_weights(const float* __restrict__ w1,
                             const float* __restrict__ l2m_w2,
                             const float* __restrict__ l1m_w2,
                             const float* __restrict__ l1a_w1,
                             const float* __restrict__ l1a_w2,
                             const float* __restrict__ l2a_w1,
                             const float* __restrict__ l2a_w2,
                             unsigned short* __restrict__ wp,
                             unsigned short* __restrict__ wq,
                             unsigned short* __restrict__ w2t1,
                             unsigned short* __restrict__ w2t2,
                             unsigned short* __restrict__ aw1t,
                             unsigned short* __restrict__ aw2t,
                             unsigned short* __restrict__ bw1t,
                             unsigned short* __restrict__ bw2t)
{
    int i0 = blockIdx.x * 256 + threadIdx.x;
    int stride = gridDim.x * 256;
    for (int idx = i0; idx < 128 * 224; idx += stride) {
        int n = idx / 224, k = idx - n * 224;
        float vp = 0.f, vq = 0.f;
        if (k < 64)        { vp = w1[k * 128 + n] - w1[(64 + k) * 128 + n];
                             vq = w1[(64 + k) * 128 + n]; }
        else if (k < 128)  { vp = w1[(130 + k - 64) * 128 + n]; }
        else if (k < 130)  { vp = -w1[(128 + (k - 128)) * 128 + n];
                             vq =  w1[(128 + (k - 128)) * 128 + n]; }
        wp[idx] = f2bf(vp);
        wq[idx] = f2bf(vq);
    }
    for (int idx = i0; idx < 64 * 128; idx += stride) {
        int n = idx >> 7, k = idx & 127;
        w2t1[idx] = f2bf(l1m_w2[k * 64 + n]);
        w2t2[idx] = f2bf(l2m_w2[k * 64 + n]);
        aw2t[idx] = f2bf(l1a_w2[k * 64 + n]);
        bw2t[idx] = f2bf(l2a_w2[k * 64 + n]);
    }
    for (int idx = i0; idx < 128 * 64; idx += stride) {
        int n = idx >> 6, k = idx & 63;
        aw1t[idx] = f2bf(l1a_w1[k * 128 + n]);
    }
    for (int idx = i0; idx < 128 * 128; idx += stride) {
        int n = idx >> 7, k = idx & 127;
        bw1t[idx] = f2bf(l2a_w1[k * 128 + n]);
    }
}

// ---------------------------------------------------------------------------
// node_u: U[n] = pos[n]@l1m_w1 (col side); Un[n] = b1 - U[n] (row side).
// Then L1 hidden = relu(Un[row] + U[col]).
// ---------------------------------------------------------------------------
__global__ __launch_bounds__(256) void node_u(const float* __restrict__ pos,
                                              const float* __restrict__ w1,
                                              const float* __restrict__ b1,
                                              unsigned short* __restrict__ U,
                                              unsigned short* __restrict__ Un)
{
    int t = blockIdx.x * 256 + threadIdx.x;
    int n = t >> 2, part = t & 3;
    if (n >= N_NODESC) return;
    float2 p = *(const float2*)(pos + 2 * (size_t)n);
    const float4* wa = (const float4*)(w1 + part * 32);
    const float4* wb = (const float4*)(w1 + 128 + part * 32);
    const float4* bb = (const float4*)(b1 + part * 32);
    unsigned* Uw  = (unsigned*)U  + (size_t)n * 64 + part * 16;
    unsigned* Unw = (unsigned*)Un + (size_t)n * 64 + part * 16;
    #pragma unroll
    for (int q = 0; q < 8; ++q) {
        float4 a = wa[q], b = wb[q], f = bb[q];
        float h0 = fmaf(p.x, a.x, p.y * b.x);
        float h1 = fmaf(p.x, a.y, p.y * b.y);
        float h2 = fmaf(p.x, a.z, p.y * b.z);
        float h3 = fmaf(p.x, a.w, p.y * b.w);
        Uw[2 * q]      = pack2(h0, h1);
        Uw[2 * q + 1]  = pack2(h2, h3);
        Unw[2 * q]     = pack2(f.x - h0, f.y - h1);
        Unw[2 * q + 1] = pack2(f.z - h2, f.w - h3);
    }
}

// ---------------------------------------------------------------------------
// edge_mlp (shared by L1 and L2): per tile of 128 sorted edges,
//   h = relu(Rr[row] + Cc[col]) -> bf16 H ; H @ w2t^T (MFMA K=128) ;
//   LDS transpose ; run-merged atomic segment-sum.
// TILES tiles/block, register-staged double-buffered pipeline, lgkm-only
// barriers so staged global loads stay in flight across barriers.
// Dynamic LDS: H[2][128*136] shorts + rows[2][128] ints = 70656 B.
// ---------------------------------------------------------------------------
#define EM_LDS (2 * 128 * 136 * 2 + 2 * 128 * 4)

__global__ __launch_bounds__(512, 4) void edge_mlp(
    const int2* __restrict__ eg,
    const unsigned short* __restrict__ Rr,   // row-side [N][128] (bias folded)
    const unsigned short* __restrict__ Cc,   // col-side [N][128]
    const unsigned short* __restrict__ w2t,  // [64][128]
    float* __restrict__ sumout)              // [N][64]
{
    extern __shared__ char smem[];
    unsigned short* H0 = (unsigned short*)smem;
    unsigned short* H1 = H0 + 128 * 136;
    int* rows0 = (int*)(smem + 2 * 128 * 136 * 2);
    int* rows1 = rows0 + 128;

    const int tid = threadIdx.x;
    const int el = tid >> 2, part = tid & 3;
    const int lane = tid & 63, l15 = lane & 15, l4 = lane >> 4;
    const int wave = tid >> 6;
    const int mh = (wave >> 2) * 64;
    const int nw = (wave & 3) * 16;
    const size_t base = (size_t)blockIdx.x * (TILES * 128);

    // B-operand fragments hoisted out of the tile loop
    bf16x8 bfrag[4];
    #pragma unroll
    for (int k = 0; k < 4; ++k)
        bfrag[k] = *(const bf16x8*)(w2t + (nw + l15) * 128 + k * 32 + l4 * 8);

    uint4 sR[2][4], sC[2][4];
    int2 e2[2];

    e2[0] = eg[base + el];
    e2[1] = eg[base + 128 + el];
    {
        const uint4* pr = (const uint4*)(Rr + (size_t)e2[0].x * 128 + part * 32);
        const uint4* pc = (const uint4*)(Cc + (size_t)e2[0].y * 128 + part * 32);
        #pragma unroll
        for (int q = 0; q < 4; ++q) { sR[0][q] = pr[q]; sC[0][q] = pc[q]; }
    }

    #pragma unroll
    for (int t = 0; t < TILES; ++t) {
        const int b = t & 1;
        unsigned short* Hc = b ? H1 : H0;
        int* rowsc = b ? rows1 : rows0;
        const int rcur = e2[b].x;

        if (t + 1 < TILES) {   // issue next tile's gathers (stay in flight)
            const uint4* pr = (const uint4*)(Rr + (size_t)e2[b ^ 1].x * 128 + part * 32);
            const uint4* pc = (const uint4*)(Cc + (size_t)e2[b ^ 1].y * 128 + part * 32);
            #pragma unroll
            for (int q = 0; q < 4; ++q) { sR[b ^ 1][q] = pr[q]; sC[b ^ 1][q] = pc[q]; }
        }
        if (t + 2 < TILES) e2[b] = eg[base + (size_t)(t + 2) * 128 + el];

        // pack h = relu(R + C) into H[b]
        if (part == 0) rowsc[el] = rcur;
        {
            uint4* Hw = (uint4*)((unsigned*)Hc + el * 68 + part * 16);
            #pragma unroll
            for (int q = 0; q < 4; ++q) {
                uint4 pv = sR[b][q], qv = sC[b][q];
                unsigned w0 = pack2(fmaxf(bflo(pv.x) + bflo(qv.x), 0.f),
                                    fmaxf(bfhi(pv.x) + bfhi(qv.x), 0.f));
                unsigned w1v = pack2(fmaxf(bflo(pv.y) + bflo(qv.y), 0.f),
                                     fmaxf(bfhi(pv.y) + bfhi(qv.y), 0.f));
                unsigned w2v = pack2(fmaxf(bflo(pv.z) + bflo(qv.z), 0.f),
                                     fmaxf(bfhi(pv.z) + bfhi(qv.z), 0.f));
                unsigned w3v = pack2(fmaxf(bflo(pv.w) + bflo(qv.w), 0.f),
                                     fmaxf(bfhi(pv.w) + bfhi(qv.w), 0.f));
                Hw[q] = make_uint4(w0, w1v, w2v, w3v);
            }
        }
        LBARRIER();

        f32x4 acc[4];
        #pragma unroll
        for (int m = 0; m < 4; ++m) acc[m] = (f32x4){0.f, 0.f, 0.f, 0.f};
        #pragma unroll
        for (int k = 0; k < 4; ++k) {
            int kb = k * 32 + l4 * 8;
            #pragma unroll
            for (int m = 0; m < 4; ++m) {
                bf16x8 a = *(const bf16x8*)(Hc + (mh + m * 16 + l15) * 136 + kb);
                acc[m] = __builtin_amdgcn_mfma_f32_16x16x32_bf16(a, bfrag[k], acc[m], 0, 0, 0);
            }
        }
        LBARRIER();   // all H[b] reads done before S overwrite

        float* S = (float*)Hc;   // [128][68]
        #pragma unroll
        for (int m = 0; m < 4; ++m) {
            int rb = mh + m * 16 + l4 * 4;
            #pragma unroll
            for (int r = 0; r < 4; ++r)
                S[(rb + r) * 68 + nw + l15] = acc[m][r];
        }
        LBARRIER();

        {   // run-merged segment reduction: thread = (col=lane, group=wave)
            const int c = lane;
            const int e0g = wave * 16;
            float sv[16];
            #pragma unroll
            for (int r = 0; r < 16; ++r) sv[r] = S[(e0g + r) * 68 + c];
            int rw[16];
            #pragma unroll
            for (int r = 0; r < 16; ++r)
                rw[r] = __builtin_amdgcn_readfirstlane(rowsc[e0g + r]);
            int cur = rw[0];
            float v = sv[0];
            #pragma unroll
            for (int r = 1; r < 16; ++r) {
                if (rw[r] == cur) { v += sv[r]; }
                else { unsafeAtomicAdd(sumout + (size_t)cur * 64 + c, v); cur = rw[r]; v = sv[r]; }
            }
            unsafeAtomicAdd(sumout + (size_t)cur * 64 + c, v);
        }
        // next iter packs the other H buffer; its last readers finished
        // before this tile's barriers -> no extra barrier needed.
    }
}

// ---------------------------------------------------------------------------
// ctx = MLP(mean(m1)+l1m_b2)  (64 -> 128 -> 64), MFMA, 128 nodes/block
// ---------------------------------------------------------------------------
__global__ __launch_bounds__(512) void ctx_mfma(
    const float* __restrict__ sum1, const float* __restrict__ cnt,
    const float* __restrict__ mb2,
    const unsigned short* __restrict__ aw1t, const float* __restrict__ ab1,
    const unsigned short* __restrict__ aw2t, const float* __restrict__ ab2,
    float* __restrict__ ctxout)
{
    __shared__ unsigned short A[128 * 72];
    __shared__ unsigned short H[128 * 136];
    const int tid = threadIdx.x;
    const int nb = blockIdx.x * 128;

    {
        int nl = tid >> 2, part = tid & 3;
        int n = nb + nl; if (n >= N_NODESC) n = N_NODESC - 1;
        float inv = 1.0f / fmaxf(cnt[n], 1.0f);
        const float4* s = (const float4*)(sum1 + (size_t)n * CTXD + part * 16);
        const float4* m = (const float4*)(mb2 + part * 16);
        unsigned* Aw = (unsigned*)A + nl * 36 + part * 8;
        #pragma unroll
        for (int q = 0; q < 4; ++q) {
            float4 v = s[q]; float4 b = m[q];
            Aw[2 * q]     = pack2(fmaf(v.x, inv, b.x), fmaf(v.y, inv, b.y));
            Aw[2 * q + 1] = pack2(fmaf(v.z, inv, b.z), fmaf(v.w, inv, b.w));
        }
    }
    __syncthreads();

    const int lane = tid & 63, l15 = lane & 15, l4 = lane >> 4;
    const int wave = tid >> 6;
    const int mh = (wave >> 2) * 64;
    const int nq = (wave & 3) * 32;

    f32x4 acc[4][2];
    #pragma unroll
    for (int m = 0; m < 4; ++m)
        #pragma unroll
        for (int n = 0; n < 2; ++n) acc[m][n] = (f32x4){0.f, 0.f, 0.f, 0.f};

    #pragma unroll
    for (int kc = 0; kc < 2; ++kc) {
        int kb = kc * 32 + l4 * 8;
        bf16x8 b0 = *(const bf16x8*)(aw1t + (nq + l15) * 64 + kb);
        bf16x8 b1v = *(const bf16x8*)(aw1t + (nq + 16 + l15) * 64 + kb);
        #pragma unroll
        for (int m = 0; m < 4; ++m) {
            bf16x8 a = *(const bf16x8*)(A + (mh + m * 16 + l15) * 72 + kb);
            acc[m][0] = __builtin_amdgcn_mfma_f32_16x16x32_bf16(a, b0, acc[m][0], 0, 0, 0);
            acc[m][1] = __builtin_amdgcn_mfma_f32_16x16x32_bf16(a, b1v, acc[m][1], 0, 0, 0);
        }
    }
    float bv0 = ab1[nq + l15], bv1 = ab1[nq + 16 + l15];
    #pragma unroll
    for (int m = 0; m < 4; ++m) {
        int rb = mh + m * 16 + l4 * 4;
        #pragma unroll
        for (int nn = 0; nn < 2; ++nn) {
            float bv = nn ? bv1 : bv0;
            int col = nq + nn * 16 + l15;
            #pragma unroll
            for (int r = 0; r < 4; ++r)
                H[(rb + r) * 136 + col] = f2bf(fmaxf(acc[m][nn][r] + bv, 0.f));
        }
    }
    __syncthreads();

    const int nw = (wave & 3) * 16;
    f32x4 acc2[4];
    #pragma unroll
    for (int m = 0; m < 4; ++m) acc2[m] = (f32x4){0.f, 0.f, 0.f, 0.f};
    #pragma unroll
    for (int kc = 0; kc < 4; ++kc) {
        int kb = kc * 32 + l4 * 8;
        bf16x8 b = *(const bf16x8*)(aw2t + (nw + l15) * 128 + kb);
        #pragma unroll
        for (int m = 0; m < 4; ++m) {
            bf16x8 a = *(const bf16x8*)(H + (mh + m * 16 + l15) * 136 + kb);
            acc2[m] = __builtin_amdgcn_mfma_f32_16x16x32_bf16(a, b, acc2[m], 0, 0, 0);
        }
    }
    float b2 = ab2[nw + l15];
    #pragma unroll
    for (int m = 0; m < 4; ++m) {
        int rb = mh + m * 16 + l4 * 4;
        #pragma unroll
        for (int r = 0; r < 4; ++r) {
            int node = nb + rb + r;
            if (node < N_NODESC)
                ctxout[(size_t)node * CTXD + nw + l15] = acc2[m][r] + b2;
        }
    }
}

// ---------------------------------------------------------------------------
// node_pq: P = [x|ctx|pos] @ WP + b1 ; Q = [x|..|pos] @ WQ  -> bf16 [N][128]
// ---------------------------------------------------------------------------
#define PQ_A 0
#define PQ_W 63488
#define PQ_LDS 126976

__global__ __launch_bounds__(512) void node_pq(
    const float* __restrict__ x, const float* __restrict__ ctxb,
    const float* __restrict__ pos,
    const unsigned short* __restrict__ wp, const unsigned short* __restrict__ wq,
    const float* __restrict__ b1,
    unsigned short* __restrict__ Pp, unsigned short* __restrict__ Qq)
{
    extern __shared__ char smem[];
    const int tid = threadIdx.x;
    const int nb = blockIdx.x * 128;

    {
        const int4* src = (const int4*)wp;
        for (int i = tid; i < 3584; i += 512) {
            int n = i / 28, c = i - n * 28;
            *(int4*)(smem + PQ_W + n * 496 + c * 16) = src[i];
        }
    }
    {
        int nl = tid >> 2, part = tid & 3;
        int n = nb + nl; if (n >= N_NODESC) n = N_NODESC - 1;
        unsigned* Aw = (unsigned*)(smem + PQ_A) + nl * 124 + part * 16;
        if (part < 2) {
            const float4* xs = (const float4*)(x + (size_t)n * XD + part * 32);
            #pragma unroll
            for (int q = 0; q < 8; ++q) {
                float4 v = xs[q];
                Aw[2 * q]     = pack2(v.x, v.y);
                Aw[2 * q + 1] = pack2(v.z, v.w);
            }
        } else if (part == 2) {
            const float4* cs = (const float4*)(ctxb + (size_t)n * CTXD);
            #pragma unroll
            for (int q = 0; q < 8; ++q) {
                float4 v = cs[q];
                Aw[2 * q]     = pack2(v.x, v.y);
                Aw[2 * q + 1] = pack2(v.z, v.w);
            }
        } else {
            const float4* cs = (const float4*)(ctxb + (size_t)n * CTXD + 32);
            #pragma unroll
            for (int q = 0; q < 8; ++q) {
                float4 v = cs[q];
                Aw[2 * q]     = pack2(v.x, v.y);
                Aw[2 * q + 1] = pack2(v.z, v.w);
            }
            float2 p2 = *(const float2*)(pos + 2 * (size_t)n);
            Aw[16] = pack2(p2.x, p2.y);
            #pragma unroll
            for (int z = 17; z < 64; ++z) Aw[z] = 0u;
        }
    }
    __syncthreads();

    const int lane = tid & 63, l15 = lane & 15, l4 = lane >> 4;
    const int wave = tid >> 6;
    const int mh = (wave >> 2) * 64;
    const int nq2 = wave & 3;

    f32x4 acc[4][4];
    #pragma unroll
    for (int m = 0; m < 4; ++m)
        #pragma unroll
        for (int n = 0; n < 4; ++n) acc[m][n] = (f32x4){0.f, 0.f, 0.f, 0.f};

    if (nq2 < 2) {
        const int cb = nq2 * 64;
        #pragma unroll
        for (int kc = 0; kc < 7; ++kc) {
            int ko = kc * 64 + l4 * 16;
            bf16x8 b0 = *(const bf16x8*)(smem + PQ_W + (cb + l15) * 496 + ko);
            bf16x8 b1v = *(const bf16x8*)(smem + PQ_W + (cb + 16 + l15) * 496 + ko);
            bf16x8 b2v = *(const bf16x8*)(smem + PQ_W + (cb + 32 + l15) * 496 + ko);
            bf16x8 b3v = *(const bf16x8*)(smem + PQ_W + (cb + 48 + l15) * 496 + ko);
            #pragma unroll
            for (int m = 0; m < 4; ++m) {
                bf16x8 a = *(const bf16x8*)(smem + PQ_A + (mh + m * 16 + l15) * 496 + ko);
                acc[m][0] = __builtin_amdgcn_mfma_f32_16x16x32_bf16(a, b0, acc[m][0], 0, 0, 0);
                acc[m][1] = __builtin_amdgcn_mfma_f32_16x16x32_bf16(a, b1v, acc[m][1], 0, 0, 0);
                acc[m][2] = __builtin_amdgcn_mfma_f32_16x16x32_bf16(a, b2v, acc[m][2], 0, 0, 0);
                acc[m][3] = __builtin_amdgcn_mfma_f32_16x16x32_bf16(a, b3v, acc[m][3], 0, 0, 0);
            }
        }
        #pragma unroll
        for (int nn = 0; nn < 4; ++nn) {
            int col = cb + nn * 16 + l15;
            float bb = b1[col];
            #pragma unroll
            for (int m = 0; m < 4; ++m) {
                int rb = mh + m * 16 + l4 * 4;
                #pragma unroll
                for (int r = 0; r < 4; ++r) {
                    int node = nb + rb + r;
                    if (node < N_NODESC)
                        Pp[(size_t)node * 128 + col] = f2bf(acc[m][nn][r] + bb);
                }
            }
        }
    } else {
        const int cb = (nq2 - 2) * 64;
        const int kcs[3] = {0, 1, 4};
        #pragma unroll
        for (int t = 0; t < 3; ++t) {
            int kc = kcs[t];
            int kb = kc * 32 + l4 * 8;
            bf16x8 b0 = *(const bf16x8*)(wq + (cb + l15) * 224 + kb);
            bf16x8 b1v = *(const bf16x8*)(wq + (cb + 16 + l15) * 224 + kb);
            bf16x8 b2v = *(const bf16x8*)(wq + (cb + 32 + l15) * 224 + kb);
            bf16x8 b3v = *(const bf16x8*)(wq + (cb + 48 + l15) * 224 + kb);
            #pragma unroll
            for (int m = 0; m < 4; ++m) {
                bf16x8 a = *(const bf16x8*)(smem + PQ_A + (mh + m * 16 + l15) * 496 + kb * 2);
                acc[m][0] = __builtin_amdgcn_mfma_f32_16x16x32_bf16(a, b0, acc[m][0], 0, 0, 0);
                acc[m][1] = __builtin_amdgcn_mfma_f32_16x16x32_bf16(a, b1v, acc[m][1], 0, 0, 0);
                acc[m][2] = __builtin_amdgcn_mfma_f32_16x16x32_bf16(a, b2v, acc[m][2], 0, 0, 0);
                acc[m][3] = __builtin_amdgcn_mfma_f32_16x16x32_bf16(a, b3v, acc[m][3], 0, 0, 0);
            }
        }
        #pragma unroll
        for (int nn = 0; nn < 4; ++nn) {
            int col = cb + nn * 16 + l15;
            #pragma unroll
            for (int m = 0; m < 4; ++m) {
                int rb = mh + m * 16 + l4 * 4;
                #pragma unroll
                for (int r = 0; r < 4; ++r) {
                    int node = nb + rb + r;
                    if (node < N_NODESC)
                        Qq[(size_t)node * 128 + col] = f2bf(acc[m][nn][r]);
                }
            }
        }
    }
}

// ---------------------------------------------------------------------------
// out = MLP([x, mean(m2)+l2m_b2]) (128 -> 128 -> 64), MFMA
// ---------------------------------------------------------------------------
__global__ __launch_bounds__(512) void out_mfma(
    const float* __restrict__ x, const float* __restrict__ sum2,
    const float* __restrict__ cnt, const float* __restrict__ mb2,
    const unsigned short* __restrict__ bw1t, const float* __restrict__ ab1,
    const unsigned short* __restrict__ bw2t, const float* __restrict__ ab2,
    float* __restrict__ out)
{
    extern __shared__ unsigned short sm[];
    unsigned short* A = sm;              // [128][136]
    unsigned short* H = sm + 128 * 136;  // [128][136]
    const int tid = threadIdx.x;
    const int nb = blockIdx.x * 128;

    {
        int nl = tid >> 2, part = tid & 3;
        int n = nb + nl; if (n >= N_NODESC) n = N_NODESC - 1;
        unsigned* Aw = (unsigned*)A + nl * 68 + part * 16;
        if (part < 2) {
            const float4* xs = (const float4*)(x + (size_t)n * XD + part * 32);
            #pragma unroll
            for (int q = 0; q < 8; ++q) {
                float4 v = xs[q];
                Aw[2 * q]     = pack2(v.x, v.y);
                Aw[2 * q + 1] = pack2(v.z, v.w);
            }
        } else {
            float inv = 1.0f / fmaxf(cnt[n], 1.0f);
            const float4* s = (const float4*)(sum2 + (size_t)n * OUTD + (part - 2) * 32);
            const float4* m = (const float4*)(mb2 + (part - 2) * 32);
            #pragma unroll
            for (int q = 0; q < 8; ++q) {
                float4 v = s[q]; float4 b = m[q];
                Aw[2 * q]     = pack2(fmaf(v.x, inv, b.x), fmaf(v.y, inv, b.y));
                Aw[2 * q + 1] = pack2(fmaf(v.z, inv, b.z), fmaf(v.w, inv, b.w));
            }
        }
    }
    __syncthreads();

    const int lane = tid & 63, l15 = lane & 15, l4 = lane >> 4;
    const int wave = tid >> 6;
    const int mh = (wave >> 2) * 64;
    const int nq = (wave & 3) * 32;

    f32x4 acc[4][2];
    #pragma unroll
    for (int m = 0; m < 4; ++m)
        #pragma unroll
        for (int n = 0; n < 2; ++n) acc[m][n] = (f32x4){0.f, 0.f, 0.f, 0.f};

    #pragma unroll
    for (int kc = 0; kc < 4; ++kc) {
        int kb = kc * 32 + l4 * 8;
        bf16x8 b0 = *(const bf16x8*)(bw1t + (nq + l15) * 128 + kb);
        bf16x8 b1v = *(const bf16x8*)(bw1t + (nq + 16 + l15) * 128 + kb);
        #pragma unroll
        for (int m = 0; m < 4; ++m) {
            bf16x8 a = *(const bf16x8*)(A + (mh + m * 16 + l15) * 136 + kb);
            acc[m][0] = __builtin_amdgcn_mfma_f32_16x16x32_bf16(a, b0, acc[m][0], 0, 0, 0);
            acc[m][1] = __builtin_amdgcn_mfma_f32_16x16x32_bf16(a, b1v, acc[m][1], 0, 0, 0);
        }
    }
    float bv0 = ab1[nq + l15], bv1 = ab1[nq + 16 + l15];
    #pragma unroll
    for (int m = 0; m < 4; ++m) {
        int rb = mh + m * 16 + l4 * 4;
        #pragma unroll
        for (int nn = 0; nn < 2; ++nn) {
            float bv = nn ? bv1 : bv0;
            int col = nq + nn * 16 + l15;
            #pragma unroll
            for (int r = 0; r < 4; ++r)
                H[(rb + r) * 136 + col] = f2bf(fmaxf(acc[m][nn][r] + bv, 0.f));
        }
    }
    __syncthreads();

    const int nw = (wave & 3) * 16;
    f32x4 acc2[4];
    #pragma unroll
    for (int m = 0; m < 4; ++m) acc2[m] = (f32x4){0.f, 0.f, 0.f, 0.f};
    #pragma unroll
    for (int kc = 0; kc < 4; ++kc) {
        int kb = kc * 32 + l4 * 8;
        bf16x8 b = *(const bf16x8*)(bw2t + (nw + l15) * 128 + kb);
        #pragma unroll
        for (int m = 0; m < 4; ++m) {
            bf16x8 a = *(const bf16x8*)(H + (mh + m * 16 + l15) * 136 + kb);
            acc2[m] = __builtin_amdgcn_mfma_f32_16x16x32_bf16(a, b, acc2[m], 0, 0, 0);
        }
    }
    float b2 = ab2[nw + l15];
    #pragma unroll
    for (int m = 0; m < 4; ++m) {
        int rb = mh + m * 16 + l4 * 4;
        #pragma unroll
        for (int r = 0; r < 4; ++r) {
            int node = nb + rb + r;
            if (node < N_NODESC)
                out[(size_t)node * OUTD + nw + l15] = acc2[m][r] + b2;
        }
    }
}

// ---------------------------------------------------------------------------
extern "C" void kernel_launch(void* const* d_in, const int* in_sizes, int n_in,
                              void* d_out, int out_size, void* d_ws, size_t ws_size,
                              hipStream_t stream)
{
    const float* x      = (const float*)d_in[0];
    const float* pos    = (const float*)d_in[1];
    const int*   ei     = (const int*)  d_in[2];
    const float* l1m_w1 = (const float*)d_in[3];
    const float* l1m_b1 = (const float*)d_in[4];
    const float* l1m_w2 = (const float*)d_in[5];
    const float* l1m_b2 = (const float*)d_in[6];
    const float* l1a_w1 = (const float*)d_in[7];
    const float* l1a_b1 = (const float*)d_in[8];
    const float* l1a_w2 = (const float*)d_in[9];
    const float* l1a_b2 = (const float*)d_in[10];
    const float* l2m_w1 = (const float*)d_in[11];
    const float* l2m_b1 = (const float*)d_in[12];
    const float* l2m_w2 = (const float*)d_in[13];
    const float* l2m_b2 = (const float*)d_in[14];
    const float* l2a_w1 = (const float*)d_in[15];
    const float* l2a_b1 = (const float*)d_in[16];
    const float* l2a_w2 = (const float*)d_in[17];
    const float* l2a_b2 = (const float*)d_in[18];

    float* ws    = (float*)d_ws;
    float* sum1  = ws;                                   // [N][64]
    float* sum2  = sum1 + (size_t)N_NODESC * CTXD;       // [N][64]
    float* ctxb  = sum2 + (size_t)N_NODESC * OUTD;       // [N][64]
    float* cnt_f = ctxb + (size_t)N_NODESC * CTXD;       // [NBINS]
    unsigned short* Pp   = (unsigned short*)(cnt_f + NBINS);    // [N][128]
    unsigned short* Qq   = Pp + (size_t)N_NODESC * 128;         // [N][128]
    unsigned short* Un   = Pp;   // row-side L1 table (aliases Pp, dead before node_pq)
    unsigned short* U    = Qq;   // col-side L1 table (aliases Qq)
    unsigned short* wp   = Qq + (size_t)N_NODESC * 128;         // 128*224
    unsigned short* wq   = wp + 128 * 224;
    unsigned short* w2t1 = wq + 128 * 224;               // 64*128
    unsigned short* w2t2 = w2t1 + 64 * 128;
    unsigned short* aw1t = w2t2 + 64 * 128;              // 128*64
    unsigned short* aw2t = aw1t + 128 * 64;              // 64*128
    unsigned short* bw1t = aw2t + 64 * 128;              // 128*128
    unsigned short* bw2t = bw1t + 128 * 128;             // 64*128
    int* hist  = (int*)(bw2t + 64 * 128);                // [NBINS]
    int* head  = hist + NBINS;                           // [NBINS]
    int* bsums = head + NBINS;                           // [256]
    int2* eg   = (int2*)(bsums + 256);                   // [E]

    hipMemsetAsync(d_ws, 0, (size_t)2 * N_NODESC * 64 * sizeof(float), stream);
    hipMemsetAsync(hist, 0, NBINS * sizeof(int), stream);

    hipFuncSetAttribute((const void*)edge_mlp,
                        hipFuncAttributeMaxDynamicSharedMemorySize, EM_LDS);
    hipFuncSetAttribute((const void*)node_pq,
                        hipFuncAttributeMaxDynamicSharedMemorySize, PQ_LDS);
    hipFuncSetAttribute((const void*)out_mfma,
                        hipFuncAttributeMaxDynamicSharedMemorySize, 2 * 128 * 136 * 2);

    hist_k<<<(N_EDGESC + 255) / 256, 256, 0, stream>>>(ei, hist);
    scan_a<<<NBINS / 256, 256, 0, stream>>>(hist, bsums);
    scan_b<<<1, 256, 0, stream>>>(bsums);
    scan_c<<<NBINS / 256, 256, 0, stream>>>(hist, bsums, head, cnt_f);
    scatter_k<<<(N_EDGESC + 255) / 256, 256, 0, stream>>>(ei, head, eg);

    prep_weights<<<64, 256, 0, stream>>>(l2m_w1, l2m_w2, l1m_w2,
                                         l1a_w1, l1a_w2, l2a_w1, l2a_w2,
                                         wp, wq, w2t1, w2t2, aw1t, aw2t, bw1t, bw2t);

    node_u<<<(N_NODESC * 4 + 255) / 256, 256, 0, stream>>>(pos, l1m_w1, l1m_b1, U, Un);

    edge_mlp<<<N_EDGESC / (128 * TILES), 512, EM_LDS, stream>>>(
        eg, Un, U, w2t1, sum1);

    ctx_mfma<<<(N_NODESC + 127) / 128, 512, 0, stream>>>(
        sum1, cnt_f, l1m_b2, aw1t, l1a_b1, aw2t, l1a_b2, ctxb);

    node_pq<<<(N_NODESC + 127) / 128, 512, PQ_LDS, stream>>>(
        x, ctxb, pos, wp, wq, l2m_b1, Pp, Qq);

    edge_mlp<<<N_EDGESC / (128 * TILES), 512, EM_LDS, stream>>>(
        eg, Pp, Qq, w2t2, sum2);

    out_mfma<<<(N_NODESC + 127) / 128, 512, 2 * 128 * 136 * 2, stream>>>(
        x, sum2, cnt_f, l2m_b2, bw1t, l2a_b1, bw2t, l2a_b2, (float*)d_out);
}